// Round 3
// baseline (663.975 us; speedup 1.0000x reference)
//
#include <hip/hip_runtime.h>
#include <math.h>

constexpr int cN = 2, cH = 8, cL = 2048, cS = 2048, cE = 64, cD = 64;
constexpr int cC = 128, cK = 32, cB = 32, cIT = 10;
constexpr int cNH = cN * cH;          // 16
constexpr int SK = 8;                 // split-K factor for PV
constexpr int CHUNK = cS / SK;        // 256 s per split
// TEMP = 1/sqrt(64) = 0.125 exactly

// ---------------- Kernel 1: LSH bits -------------------------------------
__global__ __launch_bounds__(256)
void k_bits(const float* __restrict__ q, const float* __restrict__ planes,
            unsigned int* __restrict__ bits)
{
    __shared__ float pl[cB * (cE + 1)];
    int tid = threadIdx.x;
    for (int i = tid; i < cB * (cE + 1); i += 256) pl[i] = planes[i];
    __syncthreads();
    int idx = blockIdx.x * 256 + tid;           // (n*H + h)*L + l
    int l = idx % cL, h = (idx / cL) % cH, n = idx / (cL * cH);
    const float* qr = q + (((size_t)n * cL + l) * cH + h) * cE;
    float qv[cE];
#pragma unroll
    for (int e4 = 0; e4 < cE / 4; ++e4) {
        float4 f = ((const float4*)qr)[e4];
        qv[4*e4+0] = f.x; qv[4*e4+1] = f.y; qv[4*e4+2] = f.z; qv[4*e4+3] = f.w;
    }
    unsigned int w = 0;
    for (int b = 0; b < cB; ++b) {
        float acc = 0.f;
#pragma unroll
        for (int e = 0; e < cE; ++e) acc = fmaf(qv[e], pl[b * (cE + 1) + e], acc);
        acc += pl[b * (cE + 1) + cE];
        if (acc > 0.f) w |= (1u << b);
    }
    bits[idx] = w;
}

// ---------------- Kernel 2: hamming k-means (one block per (n,h)) --------
// wave-aggregated ballot histogram: no per-point atomics
__global__ __launch_bounds__(1024)
void k_cluster(const unsigned int* __restrict__ bits,
               int* __restrict__ cl, int* __restrict__ counts)
{
    __shared__ unsigned int scb[cC] __attribute__((aligned(16)));
    __shared__ int scnt[cC];
    __shared__ int sbs[cC][cB];
    int tid = threadIdx.x;
    int lane = tid & 63, wid = tid >> 6;
    int nh = blockIdx.x;
    const unsigned int* bnh = bits + (size_t)nh * cL;
    // each thread owns 2 points, register-resident
    int l0 = wid * 128 + lane, l1 = l0 + 64;
    unsigned int w0 = bnh[l0], w1 = bnh[l1];
    if (tid < cC) {
        // idx0 = linspace(0, L-1, C).astype(int32): floor(i*2047/127), endpoint exact
        int i0 = (int)(((double)tid * 2047.0) / 127.0);
        scb[tid] = bnh[i0];
    }
    // per-bit lane ballots (points are fixed; compute once). lane b (&31) keeps bit b.
    unsigned long long mymb0 = 0ull, mymb1 = 0ull;
#pragma unroll
    for (int b = 0; b < cB; ++b) {
        unsigned long long m0 = __ballot((w0 >> b) & 1u);
        unsigned long long m1 = __ballot((w1 >> b) & 1u);
        if ((lane & 31) == b) { mymb0 = m0; mymb1 = m1; }
    }
    __syncthreads();
    const uint4* scb4 = (const uint4*)scb;
    int bc0 = 0, bc1 = 0;
    for (int it = 0; it <= cIT; ++it) {
        // assignment (packed key = (hamming<<8)|c -> min = lowest dist, tie lowest c)
        int best0 = 0x7fffffff, best1 = 0x7fffffff;
        for (int c4 = 0; c4 < cC / 4; ++c4) {
            uint4 cb = scb4[c4];
            int c = c4 * 4;
            best0 = min(best0, (__popc(w0 ^ cb.x) << 8) | c);
            best0 = min(best0, (__popc(w0 ^ cb.y) << 8) | (c + 1));
            best0 = min(best0, (__popc(w0 ^ cb.z) << 8) | (c + 2));
            best0 = min(best0, (__popc(w0 ^ cb.w) << 8) | (c + 3));
            best1 = min(best1, (__popc(w1 ^ cb.x) << 8) | c);
            best1 = min(best1, (__popc(w1 ^ cb.y) << 8) | (c + 1));
            best1 = min(best1, (__popc(w1 ^ cb.z) << 8) | (c + 2));
            best1 = min(best1, (__popc(w1 ^ cb.w) << 8) | (c + 3));
        }
        bc0 = best0 & 255; bc1 = best1 & 255;
        if (it == cIT) break;          // final assignment only
        // zero histograms
        if (tid < cC) scnt[tid] = 0;
        {
            int* sbsf = &sbs[0][0];
            for (int i = tid; i < cC * cB; i += 1024) sbsf[i] = 0;
        }
        __syncthreads();
        // wave-aggregated accumulate: per cluster, one ballot per point-pass
        for (int c = 0; c < cC; ++c) {
            unsigned long long m0 = __ballot(bc0 == c);
            unsigned long long m1 = __ballot(bc1 == c);
            if (m0 | m1) {
                int contrib = __popcll(m0 & mymb0) + __popcll(m1 & mymb1);
                if (lane < cB && contrib) atomicAdd(&sbs[c][lane], contrib);
                if (lane == 63)
                    atomicAdd(&scnt[c], __popcll(m0) + __popcll(m1));
            }
        }
        __syncthreads();
        // centroid update (integer-exact majority; keep old if empty)
        if (tid < cC) {
            int cnt = scnt[tid];
            if (cnt > 0) {
                unsigned int nw = 0;
                for (int b = 0; b < cB; ++b)
                    if (2 * sbs[tid][b] > cnt) nw |= (1u << b);
                scb[tid] = nw;
            }
        }
        __syncthreads();
    }
    // final: write assignments + counts
    cl[(size_t)nh * cL + l0] = bc0;
    cl[(size_t)nh * cL + l1] = bc1;
    if (tid < cC) scnt[tid] = 0;
    __syncthreads();
    for (int c = 0; c < cC; ++c) {
        unsigned long long m0 = __ballot(bc0 == c);
        unsigned long long m1 = __ballot(bc1 == c);
        if ((m0 | m1) && lane == 63)
            atomicAdd(&scnt[c], __popcll(m0) + __popcll(m1));
    }
    __syncthreads();
    if (tid < cC) counts[nh * cC + tid] = scnt[tid];
}

// ---------------- Kernel 3: cluster-mean queries Qg ----------------------
// one block (64 threads = one wave, thread = e) per (n,h,c); ascending-l sum
__global__ __launch_bounds__(64)
void k_qg(const float* __restrict__ q, const int* __restrict__ cl,
          const int* __restrict__ counts, float* __restrict__ Qg)
{
    __shared__ int scl[cL];
    int tid = threadIdx.x;
    int b = blockIdx.x;                 // (n*H + h)*C + c
    int c = b % cC, nh = b / cC;
    int h = nh % cH, n = nh / cH;
    const int* clr = cl + (size_t)nh * cL;
    for (int i = tid; i < cL; i += 64) scl[i] = clr[i];
    __syncthreads();
    const float* qb = q + ((size_t)n * cL * cH + h) * cE + tid;
    float acc = 0.f;
    for (int l = 0; l < cL; ++l) {
        if (scl[l] == c) acc += qb[(size_t)l * cH * cE];   // uniform branch
    }
    int cnt = counts[nh * cC + c];
    float cs = (float)(cnt > 0 ? cnt : 1);
    Qg[((size_t)nh * cC + c) * cE + tid] = acc / cs;
}

// ---------------- Kernel 4a: QK = Qg . k^T  (tiled GEMM, exact chains) ---
// grid = nh(16) x s-tiles(16 of 128); block 256 = 16 ty (c) x 16 tx (s)
__global__ __launch_bounds__(256)
void k_qk_gemm(const float* __restrict__ key, const float* __restrict__ Qg,
               float* __restrict__ QK)
{
    __shared__ float qgT[cE][cC + 2];      // [e][c]
    __shared__ float kT[cE][128 + 2];      // [e][s_local]
    int tid = threadIdx.x;
    int bs = blockIdx.x & 15;              // s-tile
    int nh = blockIdx.x >> 4;
    int h = nh % cH, n = nh / cH;
    const float4* qsrc = (const float4*)(Qg + (size_t)nh * cC * cE);
#pragma unroll
    for (int i = 0; i < 8; ++i) {
        int f = tid + 256 * i;
        int c = f >> 4, e4 = (f & 15) << 2;
        float4 v = qsrc[f];
        qgT[e4+0][c] = v.x; qgT[e4+1][c] = v.y; qgT[e4+2][c] = v.z; qgT[e4+3][c] = v.w;
    }
    const float* kb = key + (size_t)n * cS * cH * cE + (size_t)h * cE;
    int s0 = bs * 128;
#pragma unroll
    for (int i = 0; i < 8; ++i) {
        int f = tid + 256 * i;
        int s = f >> 4, e4 = (f & 15) << 2;
        float4 v = *(const float4*)(kb + (size_t)(s0 + s) * (cH * cE) + e4);
        kT[e4+0][s] = v.x; kT[e4+1][s] = v.y; kT[e4+2][s] = v.z; kT[e4+3][s] = v.w;
    }
    __syncthreads();
    int tx = tid & 15, ty = tid >> 4;
    float acc[8][8];
#pragma unroll
    for (int i = 0; i < 8; ++i)
#pragma unroll
        for (int j = 0; j < 8; ++j) acc[i][j] = 0.f;
    for (int e = 0; e < cE; ++e) {
        float qv[8], kv[8];
#pragma unroll
        for (int i = 0; i < 8; ++i) qv[i] = qgT[e][ty + 16 * i];
#pragma unroll
        for (int j = 0; j < 8; ++j) kv[j] = kT[e][tx + 16 * j];
#pragma unroll
        for (int i = 0; i < 8; ++i)
#pragma unroll
            for (int j = 0; j < 8; ++j)
                acc[i][j] = fmaf(qv[i], kv[j], acc[i][j]);   // ascending-e chain
    }
    float* dst = QK + (size_t)nh * cC * cS + s0;
#pragma unroll
    for (int i = 0; i < 8; ++i)
#pragma unroll
        for (int j = 0; j < 8; ++j)
            dst[(size_t)(ty + 16 * i) * cS + tx + 16 * j] = acc[i][j];
}

// ---------------- Kernel 4b: per-row top-32 + softmax -> P (in-place) ----
// one block (256 threads) per (n,h,c) row
__global__ __launch_bounds__(256)
void k_sel(float* __restrict__ QK, int* __restrict__ topk,
           float* __restrict__ abk)
{
    __shared__ float row[cS];
    __shared__ float work[cS];
    __shared__ float rv[4];
    __shared__ int   ri[4];
    __shared__ int   stopk[cK];
    __shared__ float sM, sDen;
    int tid = threadIdx.x;
    int lane = tid & 63, wid = tid >> 6;
    int b = blockIdx.x;                 // (n*H + h)*C + c
    float* qrow = QK + (size_t)b * cS;
    for (int j = 0; j < cS / 256; ++j) {
        int s = tid + j * 256;
        float v = qrow[s];
        row[s] = v; work[s] = v;
    }
    __syncthreads();
    // iterative top-32, tie -> lower index (jax.lax.top_k semantics)
    for (int itk = 0; itk < cK; ++itk) {
        float bv = -INFINITY; int bi = 0x7fffffff;
        for (int j = 0; j < cS / 256; ++j) {
            int s = tid + j * 256;
            float v = work[s];
            if (v > bv) { bv = v; bi = s; }
        }
#pragma unroll
        for (int off = 32; off; off >>= 1) {
            float ov = __shfl_xor(bv, off);
            int   oi = __shfl_xor(bi, off);
            if (ov > bv || (ov == bv && oi < bi)) { bv = ov; bi = oi; }
        }
        if (lane == 0) { rv[wid] = bv; ri[wid] = bi; }
        __syncthreads();
        if (tid == 0) {
            float v = rv[0]; int i = ri[0];
            for (int wv = 1; wv < 4; ++wv)
                if (rv[wv] > v || (rv[wv] == v && ri[wv] < i)) { v = rv[wv]; i = ri[wv]; }
            stopk[itk] = i;
            work[i] = -INFINITY;
        }
        __syncthreads();
    }
    if (tid < cK) topk[(size_t)b * cK + tid] = stopk[tid];
    // softmax over full row (TEMP=0.125 scaling exact; shift by max)
    float mv = -INFINITY;
    for (int j = 0; j < cS / 256; ++j) mv = fmaxf(mv, row[tid + j * 256]);
#pragma unroll
    for (int off = 32; off; off >>= 1) mv = fmaxf(mv, __shfl_xor(mv, off));
    if (lane == 0) rv[wid] = mv;
    __syncthreads();
    if (tid == 0) sM = fmaxf(fmaxf(rv[0], rv[1]), fmaxf(rv[2], rv[3]));
    __syncthreads();
    float M = sM;
    float psum = 0.f;
    for (int j = 0; j < cS / 256; ++j) {
        int s = tid + j * 256;
        float e = expf(0.125f * (row[s] - M));
        work[s] = e;
        psum += e;
    }
#pragma unroll
    for (int off = 32; off; off >>= 1) psum += __shfl_xor(psum, off);
    if (lane == 0) rv[wid] = psum;
    __syncthreads();
    if (tid == 0) sDen = ((rv[0] + rv[1]) + rv[2]) + rv[3];
    __syncthreads();
    float den = sDen;
    for (int j = 0; j < cS / 256; ++j) { int s = tid + j * 256; work[s] = work[s] / den; }
    __syncthreads();
    if (tid < cK) work[stopk[tid]] = 0.f;        // mask out top-k
    __syncthreads();
    // A_bottomk
    float ps = 0.f;
    for (int j = 0; j < cS / 256; ++j) ps += work[tid + j * 256];
#pragma unroll
    for (int off = 32; off; off >>= 1) ps += __shfl_xor(ps, off);
    if (lane == 0) rv[wid] = ps;
    __syncthreads();
    if (tid == 0) abk[b] = ((rv[0] + rv[1]) + rv[2]) + rv[3];
    // write P back in place (normalized, top-k zeroed)
    for (int j = 0; j < cS / 256; ++j) { int s = tid + j * 256; qrow[s] = work[s]; }
}

// ---------------- Kernel 4c: Vb_g partials = P . v (split-K GEMM) --------
// grid = nh(16) x sk(8) x ch(2);  block 256 = 16 ty (c) x 16 tx (d4)
__global__ __launch_bounds__(256)
void k_pv(const float* __restrict__ P, const float* __restrict__ val,
          float* __restrict__ part)
{
    __shared__ float pT[64][64 + 2];       // [c_local][s_sub]
    __shared__ float vT[64][cD + 4];       // [s_sub][d]
    int tid = threadIdx.x;
    int ch = blockIdx.x & 1;
    int sk = (blockIdx.x >> 1) & 7;
    int nh = blockIdx.x >> 4;
    int h = nh % cH, n = nh / cH;
    int tx = tid & 15, ty = tid >> 4;
    float acc[4][4];
#pragma unroll
    for (int i = 0; i < 4; ++i)
#pragma unroll
        for (int j = 0; j < 4; ++j) acc[i][j] = 0.f;
    const float* pb = P + ((size_t)nh * cC + ch * 64) * cS;
    const float* vb = val + (size_t)n * cS * cH * cD + (size_t)h * cD;
    for (int sub = 0; sub < CHUNK / 64; ++sub) {
        int s0 = sk * CHUNK + sub * 64;
#pragma unroll
        for (int i = 0; i < 4; ++i) {
            int f = tid + 256 * i;
            int c = f >> 4, s4 = (f & 15) << 2;
            float4 v = *(const float4*)(pb + (size_t)c * cS + s0 + s4);
            pT[c][s4+0] = v.x; pT[c][s4+1] = v.y; pT[c][s4+2] = v.z; pT[c][s4+3] = v.w;
        }
#pragma unroll
        for (int i = 0; i < 4; ++i) {
            int f = tid + 256 * i;
            int ss = f >> 4, d4 = (f & 15) << 2;
            float4 v = *(const float4*)(vb + (size_t)(s0 + ss) * (cH * cD) + d4);
            vT[ss][d4+0] = v.x; vT[ss][d4+1] = v.y; vT[ss][d4+2] = v.z; vT[ss][d4+3] = v.w;
        }
        __syncthreads();
        for (int ss = 0; ss < 64; ++ss) {
            float pv[4];
#pragma unroll
            for (int i = 0; i < 4; ++i) pv[i] = pT[ty + 16 * i][ss];
            float4 vv = *(const float4*)&vT[ss][tx * 4];
#pragma unroll
            for (int i = 0; i < 4; ++i) {
                acc[i][0] = fmaf(pv[i], vv.x, acc[i][0]);
                acc[i][1] = fmaf(pv[i], vv.y, acc[i][1]);
                acc[i][2] = fmaf(pv[i], vv.z, acc[i][2]);
                acc[i][3] = fmaf(pv[i], vv.w, acc[i][3]);
            }
        }
        __syncthreads();
    }
    float* dst = part + (((size_t)sk * cNH + nh) * cC + ch * 64) * cD;
#pragma unroll
    for (int i = 0; i < 4; ++i) {
        float4 o; o.x = acc[i][0]; o.y = acc[i][1]; o.z = acc[i][2]; o.w = acc[i][3];
        *(float4*)(dst + (size_t)(ty + 16 * i) * cD + tx * 4) = o;
    }
}

// ---------------- Kernel 4d: reduce split-K partials ---------------------
__global__ __launch_bounds__(256)
void k_red(const float* __restrict__ part, float* __restrict__ vbg)
{
    int i = blockIdx.x * 256 + threadIdx.x;      // over 16*128*64 = 131072
    float acc = 0.f;
    for (int sk = 0; sk < SK; ++sk) acc += part[(size_t)sk * (cNH * cC * cD) + i];
    vbg[i] = acc;
}

// ---------------- Kernel 5: per-query epilogue ---------------------------
// one wave (64 lanes) per query, 4 waves per block
__global__ __launch_bounds__(256)
void k_out(const float* __restrict__ q, const float* __restrict__ key,
           const float* __restrict__ val, const int* __restrict__ cl,
           const float* __restrict__ abk, const float* __restrict__ vbg,
           const int* __restrict__ topk, float* __restrict__ out)
{
    __shared__ float klds[4][cK][cE + 2];
    __shared__ float qlds[4][cE];
    __shared__ float qks[4][cK];
    __shared__ int   st[4][cK];
    int tid = threadIdx.x, lane = tid & 63, wid = tid >> 6;
    int qidx = blockIdx.x * 4 + wid;        // (n*H + h)*L + l
    int l = qidx % cL, nh = qidx / cL;
    int h = nh % cH, n = nh / cH;
    int c = cl[qidx];
    const int* tk = topk + ((size_t)nh * cC + c) * cK;
    if (lane < cK) st[wid][lane] = tk[lane];
    qlds[wid][lane] = q[(((size_t)n * cL + l) * cH + h) * cE + lane];
    __syncthreads();
    const float* kb = key + ((size_t)n * cS * cH + h) * cE;
    for (int j = 0; j < cK; ++j) {
        int t = st[wid][j];
        klds[wid][j][lane] = kb[(size_t)t * cH * cE + lane];
    }
    __syncthreads();
    if (lane < cK) {
        float acc = 0.f;
#pragma unroll
        for (int e = 0; e < cE; ++e)
            acc = fmaf(qlds[wid][e], klds[wid][lane][e], acc);
        qks[wid][lane] = acc;
    }
    __syncthreads();
    float m = -INFINITY;
#pragma unroll
    for (int j = 0; j < cK; ++j) m = fmaxf(m, qks[wid][j]);
    float den = 0.f;
    float ev[cK];
#pragma unroll
    for (int j = 0; j < cK; ++j) { float e = expf(0.125f * (qks[wid][j] - m)); ev[j] = e; den += e; }
    float scale = 1.0f - abk[(size_t)nh * cC + c];
#pragma unroll
    for (int j = 0; j < cK; ++j) ev[j] = (ev[j] / den) * scale;   // A_s
    const float* vb = val + ((size_t)n * cS * cH + h) * cD + lane;
    float acc = 0.f;
#pragma unroll
    for (int j = 0; j < cK; ++j) {
        int t = st[wid][j];
        acc = fmaf(ev[j], vb[(size_t)t * cH * cD], acc);
    }
    acc += vbg[((size_t)nh * cC + c) * cD + lane];
    out[(((size_t)n * cL + l) * cH + h) * cD + lane] = acc;       // (N,L,H,D)
    const size_t off1 = (size_t)cN * cL * cH * cD;
    const size_t off2 = off1 + (size_t)cN * cH * cL * cK;
    if (lane < cK) {
        out[off1 + (size_t)qidx * cK + lane] = (float)st[wid][lane];  // sparse_index
        out[off2 + (size_t)qidx * cK + lane] = ev[lane];              // A_topk
    }
}

// ---------------- launch -------------------------------------------------
extern "C" void kernel_launch(void* const* d_in, const int* in_sizes, int n_in,
                              void* d_out, int out_size, void* d_ws, size_t ws_size,
                              hipStream_t stream)
{
    (void)in_sizes; (void)n_in; (void)out_size; (void)ws_size;
    const float* q      = (const float*)d_in[0];
    const float* key    = (const float*)d_in[1];
    const float* val    = (const float*)d_in[2];
    const float* planes = (const float*)d_in[3];
    char* w = (char*)d_ws;
    unsigned int* bits = (unsigned int*)w;  w += (size_t)cN * cH * cL * 4;
    int*   cl     = (int*)w;                w += (size_t)cN * cH * cL * 4;
    int*   counts = (int*)w;                w += (size_t)cN * cH * cC * 4;
    float* abk    = (float*)w;              w += (size_t)cN * cH * cC * 4;
    float* Qg     = (float*)w;              w += (size_t)cN * cH * cC * cE * 4;
    float* vbg    = (float*)w;              w += (size_t)cN * cH * cC * cD * 4;
    int*   topkp  = (int*)w;                w += (size_t)cN * cH * cC * cK * 4;
    float* QK     = (float*)w;              w += (size_t)cNH * cC * cS * 4;      // 16 MB (QK -> P in place)
    float* part   = (float*)w;              w += (size_t)SK * cNH * cC * cD * 4; // 4 MB
    float* out = (float*)d_out;

    k_bits   <<<(cN * cH * cL) / 256, 256, 0, stream>>>(q, planes, bits);
    k_cluster<<<cN * cH, 1024, 0, stream>>>(bits, cl, counts);
    k_qg     <<<cN * cH * cC, 64, 0, stream>>>(q, cl, counts, Qg);
    k_qk_gemm<<<cNH * 16, 256, 0, stream>>>(key, Qg, QK);
    k_sel    <<<cNH * cC, 256, 0, stream>>>(QK, topkp, abk);
    k_pv     <<<cNH * SK * 2, 256, 0, stream>>>(QK, val, part);
    k_red    <<<(cNH * cC * cD) / 256, 256, 0, stream>>>(part, vbg);
    k_out    <<<(cN * cH * cL) / 4, 256, 0, stream>>>(q, key, val, cl, abk, vbg, topkp, out);
}

// Round 4
// 539.136 us; speedup vs baseline: 1.2316x; 1.2316x over previous
//
#include <hip/hip_runtime.h>
#include <math.h>

constexpr int cN = 2, cH = 8, cL = 2048, cS = 2048, cE = 64, cD = 64;
constexpr int cC = 128, cK = 32, cB = 32, cIT = 10;
constexpr int cNH = cN * cH;          // 16
constexpr int SK = 8;                 // split-K factor for PV
constexpr int CHUNK = cS / SK;        // 256 s per split
constexpr int TILES = 8;              // point tiles per nh in k_assign
constexpr int HW = cC * 33;           // partial hist words: sbs[128][32] + scnt[128]
// TEMP = 1/sqrt(64) = 0.125 exactly

// ---------------- Kernel 1: LSH bits -------------------------------------
__global__ __launch_bounds__(256)
void k_bits(const float* __restrict__ q, const float* __restrict__ planes,
            unsigned int* __restrict__ bits)
{
    __shared__ float pl[cB * (cE + 1)];
    int tid = threadIdx.x;
    for (int i = tid; i < cB * (cE + 1); i += 256) pl[i] = planes[i];
    __syncthreads();
    int idx = blockIdx.x * 256 + tid;           // (n*H + h)*L + l
    int l = idx % cL, h = (idx / cL) % cH, n = idx / (cL * cH);
    const float* qr = q + (((size_t)n * cL + l) * cH + h) * cE;
    float qv[cE];
#pragma unroll
    for (int e4 = 0; e4 < cE / 4; ++e4) {
        float4 f = ((const float4*)qr)[e4];
        qv[4*e4+0] = f.x; qv[4*e4+1] = f.y; qv[4*e4+2] = f.z; qv[4*e4+3] = f.w;
    }
    unsigned int w = 0;
    for (int b = 0; b < cB; ++b) {
        float acc = 0.f;
#pragma unroll
        for (int e = 0; e < cE; ++e) acc = fmaf(qv[e], pl[b * (cE + 1) + e], acc);
        acc += pl[b * (cE + 1) + cE];
        if (acc > 0.f) w |= (1u << b);
    }
    bits[idx] = w;
}

// ---------------- Kernel 2a: initial centroids ---------------------------
__global__ __launch_bounds__(256)
void k_init(const unsigned int* __restrict__ bits, unsigned int* __restrict__ cent)
{
    int i = blockIdx.x * 256 + threadIdx.x;     // nh*128 + c
    int c = i & 127, nh = i >> 7;
    // idx0 = linspace(0, L-1, C).astype(int32): floor(c*2047/127), endpoint exact
    int i0 = (int)(((double)c * 2047.0) / 127.0);
    cent[i] = bits[(size_t)nh * cL + i0];
}

// ---------------- Kernel 2b: assignment + partial histograms -------------
// grid = 16 nh x 8 tiles = 128 blocks, 256 threads (1 point each)
__global__ __launch_bounds__(256)
void k_assign(const unsigned int* __restrict__ bits,
              const unsigned int* __restrict__ cent,
              int* __restrict__ partial, int* __restrict__ cl, int write_cl)
{
    __shared__ unsigned int scb[cC] __attribute__((aligned(16)));
    __shared__ int hist[HW];      // [c*32+b] bitsums, [4096+c] counts
    int tid = threadIdx.x;
    int lane = tid & 63;
    int tile = blockIdx.x & (TILES - 1), nh = blockIdx.x / TILES;
    if (tid < cC) scb[tid] = cent[nh * cC + tid];
    for (int i = tid; i < HW; i += 256) hist[i] = 0;
    int l = tile * 256 + tid;
    unsigned int w = bits[(size_t)nh * cL + l];
    // per-lane bit ballots over this wave's 64 points (lane b&31 keeps bit b)
    unsigned long long mymb = 0ull;
#pragma unroll
    for (int b = 0; b < cB; ++b) {
        unsigned long long m = __ballot((w >> b) & 1u);
        if ((lane & 31) == b) mymb = m;
    }
    __syncthreads();
    const uint4* scb4 = (const uint4*)scb;
    // packed key = (hamming<<8)|c -> min = lowest dist, tie lowest c
    int best = 0x7fffffff;
    for (int c4 = 0; c4 < cC / 4; ++c4) {
        uint4 cb = scb4[c4];
        int c = c4 * 4;
        best = min(best, (__popc(w ^ cb.x) << 8) | c);
        best = min(best, (__popc(w ^ cb.y) << 8) | (c + 1));
        best = min(best, (__popc(w ^ cb.z) << 8) | (c + 2));
        best = min(best, (__popc(w ^ cb.w) << 8) | (c + 3));
    }
    int bc = best & 255;
    if (write_cl) cl[(size_t)nh * cL + l] = bc;
    // wave-aggregated histogram into LDS (integer atomics: deterministic)
    for (int c = 0; c < cC; ++c) {
        unsigned long long m = __ballot(bc == c);
        if (m) {
            if (lane < cB) {
                int contrib = __popcll(m & mymb);
                if (contrib) atomicAdd(&hist[c * 32 + lane], contrib);
            }
            if (lane == 63) atomicAdd(&hist[4096 + c], __popcll(m));
        }
    }
    __syncthreads();
    int* dst = partial + (size_t)(nh * TILES + tile) * HW;
    for (int i = tid; i < HW; i += 256) dst[i] = hist[i];
}

// ---------------- Kernel 2c: centroid update / final counts --------------
// grid = 16 blocks x 128 threads (thread = cluster)
__global__ __launch_bounds__(128)
void k_update(const int* __restrict__ partial, unsigned int* __restrict__ cent,
              int* __restrict__ counts, int mode)
{
    int c = threadIdx.x, nh = blockIdx.x;
    int cnt = 0;
    int bs[cB];
#pragma unroll
    for (int b = 0; b < cB; ++b) bs[b] = 0;
    for (int t = 0; t < TILES; ++t) {
        const int* p = partial + (size_t)(nh * TILES + t) * HW;
        cnt += p[4096 + c];
#pragma unroll
        for (int b = 0; b < cB; ++b) bs[b] += p[c * 32 + b];
    }
    if (mode == 0) {
        if (cnt > 0) {                       // keep old centroid if empty
            unsigned int nw = 0;
#pragma unroll
            for (int b = 0; b < cB; ++b)
                if (2 * bs[b] > cnt) nw |= (1u << b);
            cent[nh * cC + c] = nw;
        }
    } else {
        counts[nh * cC + c] = cnt;
    }
}

// ---------------- Kernel 3: cluster-mean queries Qg ----------------------
// one block (64 threads = one wave, thread = e) per (n,h,c); ascending-l sum
__global__ __launch_bounds__(64)
void k_qg(const float* __restrict__ q, const int* __restrict__ cl,
          const int* __restrict__ counts, float* __restrict__ Qg)
{
    __shared__ int scl[cL];
    int tid = threadIdx.x;
    int b = blockIdx.x;                 // (n*H + h)*C + c
    int c = b % cC, nh = b / cC;
    int h = nh % cH, n = nh / cH;
    const int* clr = cl + (size_t)nh * cL;
    for (int i = tid; i < cL; i += 64) scl[i] = clr[i];
    __syncthreads();
    const float* qb = q + ((size_t)n * cL * cH + h) * cE + tid;
    float acc = 0.f;
    for (int l = 0; l < cL; ++l) {
        if (scl[l] == c) acc += qb[(size_t)l * cH * cE];   // uniform branch
    }
    int cnt = counts[nh * cC + c];
    float cs = (float)(cnt > 0 ? cnt : 1);
    Qg[((size_t)nh * cC + c) * cE + tid] = acc / cs;
}

// ---------------- Kernel 4a: QK = Qg . k^T  (tiled GEMM, exact chains) ---
// grid = nh(16) x s-tiles(16 of 128); block 256 = 16 ty (c) x 16 tx (s)
__global__ __launch_bounds__(256)
void k_qk_gemm(const float* __restrict__ key, const float* __restrict__ Qg,
               float* __restrict__ QK)
{
    __shared__ float qgT[cE][cC + 2];      // [e][c]
    __shared__ float kT[cE][128 + 2];      // [e][s_local]
    int tid = threadIdx.x;
    int bs = blockIdx.x & 15;              // s-tile
    int nh = blockIdx.x >> 4;
    int h = nh % cH, n = nh / cH;
    const float4* qsrc = (const float4*)(Qg + (size_t)nh * cC * cE);
#pragma unroll
    for (int i = 0; i < 8; ++i) {
        int f = tid + 256 * i;
        int c = f >> 4, e4 = (f & 15) << 2;
        float4 v = qsrc[f];
        qgT[e4+0][c] = v.x; qgT[e4+1][c] = v.y; qgT[e4+2][c] = v.z; qgT[e4+3][c] = v.w;
    }
    const float* kb = key + (size_t)n * cS * cH * cE + (size_t)h * cE;
    int s0 = bs * 128;
#pragma unroll
    for (int i = 0; i < 8; ++i) {
        int f = tid + 256 * i;
        int s = f >> 4, e4 = (f & 15) << 2;
        float4 v = *(const float4*)(kb + (size_t)(s0 + s) * (cH * cE) + e4);
        kT[e4+0][s] = v.x; kT[e4+1][s] = v.y; kT[e4+2][s] = v.z; kT[e4+3][s] = v.w;
    }
    __syncthreads();
    int tx = tid & 15, ty = tid >> 4;
    float acc[8][8];
#pragma unroll
    for (int i = 0; i < 8; ++i)
#pragma unroll
        for (int j = 0; j < 8; ++j) acc[i][j] = 0.f;
    for (int e = 0; e < cE; ++e) {
        float qv[8], kv[8];
#pragma unroll
        for (int i = 0; i < 8; ++i) qv[i] = qgT[e][ty + 16 * i];
#pragma unroll
        for (int j = 0; j < 8; ++j) kv[j] = kT[e][tx + 16 * j];
#pragma unroll
        for (int i = 0; i < 8; ++i)
#pragma unroll
            for (int j = 0; j < 8; ++j)
                acc[i][j] = fmaf(qv[i], kv[j], acc[i][j]);   // ascending-e chain
    }
    float* dst = QK + (size_t)nh * cC * cS + s0;
#pragma unroll
    for (int i = 0; i < 8; ++i)
#pragma unroll
        for (int j = 0; j < 8; ++j)
            dst[(size_t)(ty + 16 * i) * cS + tx + 16 * j] = acc[i][j];
}

// ---------------- Kernel 4b: per-row top-32 + softmax -> P (in-place) ----
// one block (256 threads) per (n,h,c) row
__global__ __launch_bounds__(256)
void k_sel(float* __restrict__ QK, int* __restrict__ topk,
           float* __restrict__ abk)
{
    __shared__ float row[cS];
    __shared__ float work[cS];
    __shared__ float rv[4];
    __shared__ int   ri[4];
    __shared__ int   stopk[cK];
    __shared__ float sM, sDen;
    int tid = threadIdx.x;
    int lane = tid & 63, wid = tid >> 6;
    int b = blockIdx.x;                 // (n*H + h)*C + c
    float* qrow = QK + (size_t)b * cS;
    for (int j = 0; j < cS / 256; ++j) {
        int s = tid + j * 256;
        float v = qrow[s];
        row[s] = v; work[s] = v;
    }
    __syncthreads();
    // iterative top-32, tie -> lower index (jax.lax.top_k semantics)
    for (int itk = 0; itk < cK; ++itk) {
        float bv = -INFINITY; int bi = 0x7fffffff;
        for (int j = 0; j < cS / 256; ++j) {
            int s = tid + j * 256;
            float v = work[s];
            if (v > bv) { bv = v; bi = s; }
        }
#pragma unroll
        for (int off = 32; off; off >>= 1) {
            float ov = __shfl_xor(bv, off);
            int   oi = __shfl_xor(bi, off);
            if (ov > bv || (ov == bv && oi < bi)) { bv = ov; bi = oi; }
        }
        if (lane == 0) { rv[wid] = bv; ri[wid] = bi; }
        __syncthreads();
        if (tid == 0) {
            float v = rv[0]; int i = ri[0];
            for (int wv = 1; wv < 4; ++wv)
                if (rv[wv] > v || (rv[wv] == v && ri[wv] < i)) { v = rv[wv]; i = ri[wv]; }
            stopk[itk] = i;
            work[i] = -INFINITY;
        }
        __syncthreads();
    }
    if (tid < cK) topk[(size_t)b * cK + tid] = stopk[tid];
    // softmax over full row (TEMP=0.125 scaling exact; shift by max)
    float mv = -INFINITY;
    for (int j = 0; j < cS / 256; ++j) mv = fmaxf(mv, row[tid + j * 256]);
#pragma unroll
    for (int off = 32; off; off >>= 1) mv = fmaxf(mv, __shfl_xor(mv, off));
    if (lane == 0) rv[wid] = mv;
    __syncthreads();
    if (tid == 0) sM = fmaxf(fmaxf(rv[0], rv[1]), fmaxf(rv[2], rv[3]));
    __syncthreads();
    float M = sM;
    float psum = 0.f;
    for (int j = 0; j < cS / 256; ++j) {
        int s = tid + j * 256;
        float e = expf(0.125f * (row[s] - M));
        work[s] = e;
        psum += e;
    }
#pragma unroll
    for (int off = 32; off; off >>= 1) psum += __shfl_xor(psum, off);
    if (lane == 0) rv[wid] = psum;
    __syncthreads();
    if (tid == 0) sDen = ((rv[0] + rv[1]) + rv[2]) + rv[3];
    __syncthreads();
    float den = sDen;
    for (int j = 0; j < cS / 256; ++j) { int s = tid + j * 256; work[s] = work[s] / den; }
    __syncthreads();
    if (tid < cK) work[stopk[tid]] = 0.f;        // mask out top-k
    __syncthreads();
    // A_bottomk
    float ps = 0.f;
    for (int j = 0; j < cS / 256; ++j) ps += work[tid + j * 256];
#pragma unroll
    for (int off = 32; off; off >>= 1) ps += __shfl_xor(ps, off);
    if (lane == 0) rv[wid] = ps;
    __syncthreads();
    if (tid == 0) abk[b] = ((rv[0] + rv[1]) + rv[2]) + rv[3];
    // write P back in place (normalized, top-k zeroed)
    for (int j = 0; j < cS / 256; ++j) { int s = tid + j * 256; qrow[s] = work[s]; }
}

// ---------------- Kernel 4c: Vb_g partials = P . v (split-K GEMM) --------
// grid = nh(16) x sk(8) x ch(2);  block 256 = 16 ty (c) x 16 tx (d4)
__global__ __launch_bounds__(256)
void k_pv(const float* __restrict__ P, const float* __restrict__ val,
          float* __restrict__ part)
{
    __shared__ float pT[64][64 + 2];       // [c_local][s_sub]
    __shared__ float vT[64][cD + 4];       // [s_sub][d]
    int tid = threadIdx.x;
    int ch = blockIdx.x & 1;
    int sk = (blockIdx.x >> 1) & 7;
    int nh = blockIdx.x >> 4;
    int h = nh % cH, n = nh / cH;
    int tx = tid & 15, ty = tid >> 4;
    float acc[4][4];
#pragma unroll
    for (int i = 0; i < 4; ++i)
#pragma unroll
        for (int j = 0; j < 4; ++j) acc[i][j] = 0.f;
    const float* pb = P + ((size_t)nh * cC + ch * 64) * cS;
    const float* vb = val + (size_t)n * cS * cH * cD + (size_t)h * cD;
    for (int sub = 0; sub < CHUNK / 64; ++sub) {
        int s0 = sk * CHUNK + sub * 64;
#pragma unroll
        for (int i = 0; i < 4; ++i) {
            int f = tid + 256 * i;
            int c = f >> 4, s4 = (f & 15) << 2;
            float4 v = *(const float4*)(pb + (size_t)c * cS + s0 + s4);
            pT[c][s4+0] = v.x; pT[c][s4+1] = v.y; pT[c][s4+2] = v.z; pT[c][s4+3] = v.w;
        }
#pragma unroll
        for (int i = 0; i < 4; ++i) {
            int f = tid + 256 * i;
            int ss = f >> 4, d4 = (f & 15) << 2;
            float4 v = *(const float4*)(vb + (size_t)(s0 + ss) * (cH * cD) + d4);
            vT[ss][d4+0] = v.x; vT[ss][d4+1] = v.y; vT[ss][d4+2] = v.z; vT[ss][d4+3] = v.w;
        }
        __syncthreads();
        for (int ss = 0; ss < 64; ++ss) {
            float pv[4];
#pragma unroll
            for (int i = 0; i < 4; ++i) pv[i] = pT[ty + 16 * i][ss];
            float4 vv = *(const float4*)&vT[ss][tx * 4];
#pragma unroll
            for (int i = 0; i < 4; ++i) {
                acc[i][0] = fmaf(pv[i], vv.x, acc[i][0]);
                acc[i][1] = fmaf(pv[i], vv.y, acc[i][1]);
                acc[i][2] = fmaf(pv[i], vv.z, acc[i][2]);
                acc[i][3] = fmaf(pv[i], vv.w, acc[i][3]);
            }
        }
        __syncthreads();
    }
    float* dst = part + (((size_t)sk * cNH + nh) * cC + ch * 64) * cD;
#pragma unroll
    for (int i = 0; i < 4; ++i) {
        float4 o; o.x = acc[i][0]; o.y = acc[i][1]; o.z = acc[i][2]; o.w = acc[i][3];
        *(float4*)(dst + (size_t)(ty + 16 * i) * cD + tx * 4) = o;
    }
}

// ---------------- Kernel 4d: reduce split-K partials ---------------------
__global__ __launch_bounds__(256)
void k_red(const float* __restrict__ part, float* __restrict__ vbg)
{
    int i = blockIdx.x * 256 + threadIdx.x;      // over 16*128*64 = 131072
    float acc = 0.f;
    for (int sk = 0; sk < SK; ++sk) acc += part[(size_t)sk * (cNH * cC * cD) + i];
    vbg[i] = acc;
}

// ---------------- Kernel 5: per-query epilogue ---------------------------
// one wave (64 lanes) per query, 4 waves per block
__global__ __launch_bounds__(256)
void k_out(const float* __restrict__ q, const float* __restrict__ key,
           const float* __restrict__ val, const int* __restrict__ cl,
           const float* __restrict__ abk, const float* __restrict__ vbg,
           const int* __restrict__ topk, float* __restrict__ out)
{
    __shared__ float klds[4][cK][cE + 2];
    __shared__ float qlds[4][cE];
    __shared__ float qks[4][cK];
    __shared__ int   st[4][cK];
    int tid = threadIdx.x, lane = tid & 63, wid = tid >> 6;
    int qidx = blockIdx.x * 4 + wid;        // (n*H + h)*L + l
    int l = qidx % cL, nh = qidx / cL;
    int h = nh % cH, n = nh / cH;
    int c = cl[qidx];
    const int* tk = topk + ((size_t)nh * cC + c) * cK;
    if (lane < cK) st[wid][lane] = tk[lane];
    qlds[wid][lane] = q[(((size_t)n * cL + l) * cH + h) * cE + lane];
    __syncthreads();
    const float* kb = key + ((size_t)n * cS * cH + h) * cE;
    for (int j = 0; j < cK; ++j) {
        int t = st[wid][j];
        klds[wid][j][lane] = kb[(size_t)t * cH * cE + lane];
    }
    __syncthreads();
    if (lane < cK) {
        float acc = 0.f;
#pragma unroll
        for (int e = 0; e < cE; ++e)
            acc = fmaf(qlds[wid][e], klds[wid][lane][e], acc);
        qks[wid][lane] = acc;
    }
    __syncthreads();
    float m = -INFINITY;
#pragma unroll
    for (int j = 0; j < cK; ++j) m = fmaxf(m, qks[wid][j]);
    float den = 0.f;
    float ev[cK];
#pragma unroll
    for (int j = 0; j < cK; ++j) { float e = expf(0.125f * (qks[wid][j] - m)); ev[j] = e; den += e; }
    float scale = 1.0f - abk[(size_t)nh * cC + c];
#pragma unroll
    for (int j = 0; j < cK; ++j) ev[j] = (ev[j] / den) * scale;   // A_s
    const float* vb = val + ((size_t)n * cS * cH + h) * cD + lane;
    float acc = 0.f;
#pragma unroll
    for (int j = 0; j < cK; ++j) {
        int t = st[wid][j];
        acc = fmaf(ev[j], vb[(size_t)t * cH * cD], acc);
    }
    acc += vbg[((size_t)nh * cC + c) * cD + lane];
    out[(((size_t)n * cL + l) * cH + h) * cD + lane] = acc;       // (N,L,H,D)
    const size_t off1 = (size_t)cN * cL * cH * cD;
    const size_t off2 = off1 + (size_t)cN * cH * cL * cK;
    if (lane < cK) {
        out[off1 + (size_t)qidx * cK + lane] = (float)st[wid][lane];  // sparse_index
        out[off2 + (size_t)qidx * cK + lane] = ev[lane];              // A_topk
    }
}

// ---------------- launch -------------------------------------------------
extern "C" void kernel_launch(void* const* d_in, const int* in_sizes, int n_in,
                              void* d_out, int out_size, void* d_ws, size_t ws_size,
                              hipStream_t stream)
{
    (void)in_sizes; (void)n_in; (void)out_size; (void)ws_size;
    const float* q      = (const float*)d_in[0];
    const float* key    = (const float*)d_in[1];
    const float* val    = (const float*)d_in[2];
    const float* planes = (const float*)d_in[3];
    char* w = (char*)d_ws;
    unsigned int* bits = (unsigned int*)w;  w += (size_t)cN * cH * cL * 4;
    int*   cl     = (int*)w;                w += (size_t)cN * cH * cL * 4;
    int*   counts = (int*)w;                w += (size_t)cN * cH * cC * 4;
    float* abk    = (float*)w;              w += (size_t)cN * cH * cC * 4;
    float* Qg     = (float*)w;              w += (size_t)cN * cH * cC * cE * 4;
    float* vbg    = (float*)w;              w += (size_t)cN * cH * cC * cD * 4;
    int*   topkp  = (int*)w;                w += (size_t)cN * cH * cC * cK * 4;
    float* QK     = (float*)w;              w += (size_t)cNH * cC * cS * 4;      // 16 MB (QK -> P in place)
    float* part   = (float*)w;              w += (size_t)SK * cNH * cC * cD * 4; // 4 MB
    unsigned int* cent = (unsigned int*)w;  w += (size_t)cNH * cC * 4;           // 8 KB
    int*   partial = (int*)w;               w += (size_t)cNH * TILES * HW * 4;   // 2.2 MB
    float* out = (float*)d_out;

    k_bits   <<<(cN * cH * cL) / 256, 256, 0, stream>>>(q, planes, bits);
    k_init   <<<(cNH * cC) / 256, 256, 0, stream>>>(bits, cent);
    for (int it = 0; it < cIT; ++it) {
        k_assign <<<cNH * TILES, 256, 0, stream>>>(bits, cent, partial, cl, 0);
        k_update <<<cNH, 128, 0, stream>>>(partial, cent, counts, 0);
    }
    k_assign <<<cNH * TILES, 256, 0, stream>>>(bits, cent, partial, cl, 1);
    k_update <<<cNH, 128, 0, stream>>>(partial, cent, counts, 1);
    k_qg     <<<cN * cH * cC, 64, 0, stream>>>(q, cl, counts, Qg);
    k_qk_gemm<<<cNH * 16, 256, 0, stream>>>(key, Qg, QK);
    k_sel    <<<cNH * cC, 256, 0, stream>>>(QK, topkp, abk);
    k_pv     <<<cNH * SK * 2, 256, 0, stream>>>(QK, val, part);
    k_red    <<<(cNH * cC * cD) / 256, 256, 0, stream>>>(part, vbg);
    k_out    <<<(cN * cH * cL) / 4, 256, 0, stream>>>(q, key, val, cl, abk, vbg, topkp, out);
}

// Round 5
// 536.235 us; speedup vs baseline: 1.2382x; 1.0054x over previous
//
#include <hip/hip_runtime.h>
#include <math.h>

constexpr int cN = 2, cH = 8, cL = 2048, cS = 2048, cE = 64, cD = 64;
constexpr int cC = 128, cK = 32, cB = 32, cIT = 10;
constexpr int cNH = cN * cH;          // 16
constexpr int SK = 8;                 // split-K factor for PV
constexpr int CHUNK = cS / SK;        // 256 s per split
constexpr int TILES = 8;              // point tiles per nh in k_assign
constexpr int HW = cC * 33;           // partial hist words: sbs[128][32] + scnt[128]
constexpr int CG = 8;                 // cluster-groups per nh in k_qg
// TEMP = 1/sqrt(64) = 0.125 exactly

// ---------------- Kernel 1: LSH bits -------------------------------------
__global__ __launch_bounds__(256)
void k_bits(const float* __restrict__ q, const float* __restrict__ planes,
            unsigned int* __restrict__ bits)
{
    __shared__ float pl[cB * (cE + 1)];
    int tid = threadIdx.x;
    for (int i = tid; i < cB * (cE + 1); i += 256) pl[i] = planes[i];
    __syncthreads();
    int idx = blockIdx.x * 256 + tid;           // (n*H + h)*L + l
    int l = idx % cL, h = (idx / cL) % cH, n = idx / (cL * cH);
    const float* qr = q + (((size_t)n * cL + l) * cH + h) * cE;
    float qv[cE];
#pragma unroll
    for (int e4 = 0; e4 < cE / 4; ++e4) {
        float4 f = ((const float4*)qr)[e4];
        qv[4*e4+0] = f.x; qv[4*e4+1] = f.y; qv[4*e4+2] = f.z; qv[4*e4+3] = f.w;
    }
    unsigned int w = 0;
    for (int b = 0; b < cB; ++b) {
        float acc = 0.f;
#pragma unroll
        for (int e = 0; e < cE; ++e) acc = fmaf(qv[e], pl[b * (cE + 1) + e], acc);
        acc += pl[b * (cE + 1) + cE];
        if (acc > 0.f) w |= (1u << b);
    }
    bits[idx] = w;
}

// ---------------- Kernel 2a: initial centroids ---------------------------
__global__ __launch_bounds__(256)
void k_init(const unsigned int* __restrict__ bits, unsigned int* __restrict__ cent)
{
    int i = blockIdx.x * 256 + threadIdx.x;     // nh*128 + c
    int c = i & 127, nh = i >> 7;
    // idx0 = linspace(0, L-1, C).astype(int32): floor(c*2047/127), endpoint exact
    int i0 = (int)(((double)c * 2047.0) / 127.0);
    cent[i] = bits[(size_t)nh * cL + i0];
}

// ---------------- Kernel 2b: assignment + partial histograms -------------
// grid = 16 nh x 8 tiles = 128 blocks, 256 threads (1 point each)
__global__ __launch_bounds__(256)
void k_assign(const unsigned int* __restrict__ bits,
              const unsigned int* __restrict__ cent,
              int* __restrict__ partial, int* __restrict__ cl, int write_cl)
{
    __shared__ unsigned int scb[cC] __attribute__((aligned(16)));
    __shared__ int hist[HW];      // [c*32+b] bitsums, [4096+c] counts
    int tid = threadIdx.x;
    int lane = tid & 63;
    int tile = blockIdx.x & (TILES - 1), nh = blockIdx.x / TILES;
    if (tid < cC) scb[tid] = cent[nh * cC + tid];
    for (int i = tid; i < HW; i += 256) hist[i] = 0;
    int l = tile * 256 + tid;
    unsigned int w = bits[(size_t)nh * cL + l];
    // per-lane bit ballots over this wave's 64 points (lane b&31 keeps bit b)
    unsigned long long mymb = 0ull;
#pragma unroll
    for (int b = 0; b < cB; ++b) {
        unsigned long long m = __ballot((w >> b) & 1u);
        if ((lane & 31) == b) mymb = m;
    }
    __syncthreads();
    const uint4* scb4 = (const uint4*)scb;
    // packed key = (hamming<<8)|c -> min = lowest dist, tie lowest c
    int best = 0x7fffffff;
    for (int c4 = 0; c4 < cC / 4; ++c4) {
        uint4 cb = scb4[c4];
        int c = c4 * 4;
        best = min(best, (__popc(w ^ cb.x) << 8) | c);
        best = min(best, (__popc(w ^ cb.y) << 8) | (c + 1));
        best = min(best, (__popc(w ^ cb.z) << 8) | (c + 2));
        best = min(best, (__popc(w ^ cb.w) << 8) | (c + 3));
    }
    int bc = best & 255;
    if (write_cl) cl[(size_t)nh * cL + l] = bc;
    // wave-aggregated histogram into LDS (integer atomics: deterministic)
    for (int c = 0; c < cC; ++c) {
        unsigned long long m = __ballot(bc == c);
        if (m) {
            if (lane < cB) {
                int contrib = __popcll(m & mymb);
                if (contrib) atomicAdd(&hist[c * 32 + lane], contrib);
            }
            if (lane == 63) atomicAdd(&hist[4096 + c], __popcll(m));
        }
    }
    __syncthreads();
    int* dst = partial + (size_t)(nh * TILES + tile) * HW;
    for (int i = tid; i < HW; i += 256) dst[i] = hist[i];
}

// ---------------- Kernel 2c: centroid update / final counts --------------
// grid = 16 blocks x 128 threads (thread = cluster)
__global__ __launch_bounds__(128)
void k_update(const int* __restrict__ partial, unsigned int* __restrict__ cent,
              int* __restrict__ counts, int mode)
{
    int c = threadIdx.x, nh = blockIdx.x;
    int cnt = 0;
    int bs[cB];
#pragma unroll
    for (int b = 0; b < cB; ++b) bs[b] = 0;
    for (int t = 0; t < TILES; ++t) {
        const int* p = partial + (size_t)(nh * TILES + t) * HW;
        cnt += p[4096 + c];
#pragma unroll
        for (int b = 0; b < cB; ++b) bs[b] += p[c * 32 + b];
    }
    if (mode == 0) {
        if (cnt > 0) {                       // keep old centroid if empty
            unsigned int nw = 0;
#pragma unroll
            for (int b = 0; b < cB; ++b)
                if (2 * bs[b] > cnt) nw |= (1u << b);
            cent[nh * cC + c] = nw;
        }
    } else {
        counts[nh * cC + c] = cnt;
    }
}

// ---------------- Kernel 3: cluster-mean queries Qg ----------------------
// grid = 16 nh x 8 cluster-groups; block 256 = 4 waves; each wave owns 4
// consecutive clusters (lane = e). Strict ascending-l accumulation per
// cluster (bit-exact vs np sequential GEMM); q row loaded by owning wave only.
__global__ __launch_bounds__(256)
void k_qg(const float* __restrict__ q, const int* __restrict__ cl,
          const int* __restrict__ counts, float* __restrict__ Qg)
{
    __shared__ int scl[cL] __attribute__((aligned(16)));
    int tid = threadIdx.x, lane = tid & 63, wid = tid >> 6;
    int cg = blockIdx.x % CG, nh = blockIdx.x / CG;
    int h = nh % cH, n = nh / cH;
    const int* clr = cl + (size_t)nh * cL;
    for (int i = tid; i < cL; i += 256) scl[i] = clr[i];
    __syncthreads();
    int cbase = cg * (cC / CG) + wid * 4;       // 4 clusters per wave
    float acc0 = 0.f, acc1 = 0.f, acc2 = 0.f, acc3 = 0.f;
    const float* qb = q + ((size_t)n * cL * cH + h) * cE + lane;
    const int4* scl4 = (const int4*)scl;
    for (int l4 = 0; l4 < cL / 4; ++l4) {
        int4 c4 = scl4[l4];                     // broadcast LDS read
        int l = l4 * 4;
        int j0 = c4.x - cbase, j1 = c4.y - cbase,
            j2 = c4.z - cbase, j3 = c4.w - cbase;
        if ((unsigned)j0 < 4u) {                // wave-uniform branch
            float v = qb[(size_t)(l + 0) * cH * cE];
            if (j0 == 0) acc0 += v; else if (j0 == 1) acc1 += v;
            else if (j0 == 2) acc2 += v; else acc3 += v;
        }
        if ((unsigned)j1 < 4u) {
            float v = qb[(size_t)(l + 1) * cH * cE];
            if (j1 == 0) acc0 += v; else if (j1 == 1) acc1 += v;
            else if (j1 == 2) acc2 += v; else acc3 += v;
        }
        if ((unsigned)j2 < 4u) {
            float v = qb[(size_t)(l + 2) * cH * cE];
            if (j2 == 0) acc0 += v; else if (j2 == 1) acc1 += v;
            else if (j2 == 2) acc2 += v; else acc3 += v;
        }
        if ((unsigned)j3 < 4u) {
            float v = qb[(size_t)(l + 3) * cH * cE];
            if (j3 == 0) acc0 += v; else if (j3 == 1) acc1 += v;
            else if (j3 == 2) acc2 += v; else acc3 += v;
        }
    }
    const int* cnts = counts + nh * cC + cbase;
    float* dst = Qg + ((size_t)nh * cC + cbase) * cE + lane;
    {
        int c0 = cnts[0]; dst[0 * cE] = acc0 / (float)(c0 > 0 ? c0 : 1);
        int c1 = cnts[1]; dst[1 * cE] = acc1 / (float)(c1 > 0 ? c1 : 1);
        int c2 = cnts[2]; dst[2 * cE] = acc2 / (float)(c2 > 0 ? c2 : 1);
        int c3 = cnts[3]; dst[3 * cE] = acc3 / (float)(c3 > 0 ? c3 : 1);
    }
}

// ---------------- Kernel 4a: QK = Qg . k^T  (tiled GEMM, exact chains) ---
// grid = nh(16) x s-tiles(16 of 128); block 256 = 16 ty (c) x 16 tx (s)
__global__ __launch_bounds__(256)
void k_qk_gemm(const float* __restrict__ key, const float* __restrict__ Qg,
               float* __restrict__ QK)
{
    __shared__ float qgT[cE][cC + 2];      // [e][c]
    __shared__ float kT[cE][128 + 2];      // [e][s_local]
    int tid = threadIdx.x;
    int bs = blockIdx.x & 15;              // s-tile
    int nh = blockIdx.x >> 4;
    int h = nh % cH, n = nh / cH;
    const float4* qsrc = (const float4*)(Qg + (size_t)nh * cC * cE);
#pragma unroll
    for (int i = 0; i < 8; ++i) {
        int f = tid + 256 * i;
        int c = f >> 4, e4 = (f & 15) << 2;
        float4 v = qsrc[f];
        qgT[e4+0][c] = v.x; qgT[e4+1][c] = v.y; qgT[e4+2][c] = v.z; qgT[e4+3][c] = v.w;
    }
    const float* kb = key + (size_t)n * cS * cH * cE + (size_t)h * cE;
    int s0 = bs * 128;
#pragma unroll
    for (int i = 0; i < 8; ++i) {
        int f = tid + 256 * i;
        int s = f >> 4, e4 = (f & 15) << 2;
        float4 v = *(const float4*)(kb + (size_t)(s0 + s) * (cH * cE) + e4);
        kT[e4+0][s] = v.x; kT[e4+1][s] = v.y; kT[e4+2][s] = v.z; kT[e4+3][s] = v.w;
    }
    __syncthreads();
    int tx = tid & 15, ty = tid >> 4;
    float acc[8][8];
#pragma unroll
    for (int i = 0; i < 8; ++i)
#pragma unroll
        for (int j = 0; j < 8; ++j) acc[i][j] = 0.f;
    for (int e = 0; e < cE; ++e) {
        float qv[8], kv[8];
#pragma unroll
        for (int i = 0; i < 8; ++i) qv[i] = qgT[e][ty + 16 * i];
#pragma unroll
        for (int j = 0; j < 8; ++j) kv[j] = kT[e][tx + 16 * j];
#pragma unroll
        for (int i = 0; i < 8; ++i)
#pragma unroll
            for (int j = 0; j < 8; ++j)
                acc[i][j] = fmaf(qv[i], kv[j], acc[i][j]);   // ascending-e chain
    }
    float* dst = QK + (size_t)nh * cC * cS + s0;
#pragma unroll
    for (int i = 0; i < 8; ++i)
#pragma unroll
        for (int j = 0; j < 8; ++j)
            dst[(size_t)(ty + 16 * i) * cS + tx + 16 * j] = acc[i][j];
}

// ---------------- Kernel 4b: per-row top-32 + softmax -> P (in-place) ----
// one block (256 threads) per (n,h,c) row
__global__ __launch_bounds__(256)
void k_sel(float* __restrict__ QK, int* __restrict__ topk,
           float* __restrict__ abk)
{
    __shared__ float row[cS];
    __shared__ float work[cS];
    __shared__ float rv[4];
    __shared__ int   ri[4];
    __shared__ int   stopk[cK];
    __shared__ float sM, sDen;
    int tid = threadIdx.x;
    int lane = tid & 63, wid = tid >> 6;
    int b = blockIdx.x;                 // (n*H + h)*C + c
    float* qrow = QK + (size_t)b * cS;
    for (int j = 0; j < cS / 256; ++j) {
        int s = tid + j * 256;
        float v = qrow[s];
        row[s] = v; work[s] = v;
    }
    __syncthreads();
    // iterative top-32, tie -> lower index (jax.lax.top_k semantics)
    for (int itk = 0; itk < cK; ++itk) {
        float bv = -INFINITY; int bi = 0x7fffffff;
        for (int j = 0; j < cS / 256; ++j) {
            int s = tid + j * 256;
            float v = work[s];
            if (v > bv) { bv = v; bi = s; }
        }
#pragma unroll
        for (int off = 32; off; off >>= 1) {
            float ov = __shfl_xor(bv, off);
            int   oi = __shfl_xor(bi, off);
            if (ov > bv || (ov == bv && oi < bi)) { bv = ov; bi = oi; }
        }
        if (lane == 0) { rv[wid] = bv; ri[wid] = bi; }
        __syncthreads();
        if (tid == 0) {
            float v = rv[0]; int i = ri[0];
            for (int wv = 1; wv < 4; ++wv)
                if (rv[wv] > v || (rv[wv] == v && ri[wv] < i)) { v = rv[wv]; i = ri[wv]; }
            stopk[itk] = i;
            work[i] = -INFINITY;
        }
        __syncthreads();
    }
    if (tid < cK) topk[(size_t)b * cK + tid] = stopk[tid];
    // softmax over full row (TEMP=0.125 scaling exact; shift by max)
    float mv = -INFINITY;
    for (int j = 0; j < cS / 256; ++j) mv = fmaxf(mv, row[tid + j * 256]);
#pragma unroll
    for (int off = 32; off; off >>= 1) mv = fmaxf(mv, __shfl_xor(mv, off));
    if (lane == 0) rv[wid] = mv;
    __syncthreads();
    if (tid == 0) sM = fmaxf(fmaxf(rv[0], rv[1]), fmaxf(rv[2], rv[3]));
    __syncthreads();
    float M = sM;
    float psum = 0.f;
    for (int j = 0; j < cS / 256; ++j) {
        int s = tid + j * 256;
        float e = expf(0.125f * (row[s] - M));
        work[s] = e;
        psum += e;
    }
#pragma unroll
    for (int off = 32; off; off >>= 1) psum += __shfl_xor(psum, off);
    if (lane == 0) rv[wid] = psum;
    __syncthreads();
    if (tid == 0) sDen = ((rv[0] + rv[1]) + rv[2]) + rv[3];
    __syncthreads();
    float den = sDen;
    for (int j = 0; j < cS / 256; ++j) { int s = tid + j * 256; work[s] = work[s] / den; }
    __syncthreads();
    if (tid < cK) work[stopk[tid]] = 0.f;        // mask out top-k
    __syncthreads();
    // A_bottomk
    float ps = 0.f;
    for (int j = 0; j < cS / 256; ++j) ps += work[tid + j * 256];
#pragma unroll
    for (int off = 32; off; off >>= 1) ps += __shfl_xor(ps, off);
    if (lane == 0) rv[wid] = ps;
    __syncthreads();
    if (tid == 0) abk[b] = ((rv[0] + rv[1]) + rv[2]) + rv[3];
    // write P back in place (normalized, top-k zeroed)
    for (int j = 0; j < cS / 256; ++j) { int s = tid + j * 256; qrow[s] = work[s]; }
}

// ---------------- Kernel 4c: Vb_g partials = P . v (split-K GEMM) --------
// grid = nh(16) x sk(8) x ch(2);  block 256 = 16 ty (c) x 16 tx (d4)
__global__ __launch_bounds__(256)
void k_pv(const float* __restrict__ P, const float* __restrict__ val,
          float* __restrict__ part)
{
    __shared__ float pT[64][64 + 2];       // [c_local][s_sub]
    __shared__ float vT[64][cD + 4];       // [s_sub][d]
    int tid = threadIdx.x;
    int ch = blockIdx.x & 1;
    int sk = (blockIdx.x >> 1) & 7;
    int nh = blockIdx.x >> 4;
    int h = nh % cH, n = nh / cH;
    int tx = tid & 15, ty = tid >> 4;
    float acc[4][4];
#pragma unroll
    for (int i = 0; i < 4; ++i)
#pragma unroll
        for (int j = 0; j < 4; ++j) acc[i][j] = 0.f;
    const float* pb = P + ((size_t)nh * cC + ch * 64) * cS;
    const float* vb = val + (size_t)n * cS * cH * cD + (size_t)h * cD;
    for (int sub = 0; sub < CHUNK / 64; ++sub) {
        int s0 = sk * CHUNK + sub * 64;
#pragma unroll
        for (int i = 0; i < 4; ++i) {
            int f = tid + 256 * i;
            int c = f >> 4, s4 = (f & 15) << 2;
            float4 v = *(const float4*)(pb + (size_t)c * cS + s0 + s4);
            pT[c][s4+0] = v.x; pT[c][s4+1] = v.y; pT[c][s4+2] = v.z; pT[c][s4+3] = v.w;
        }
#pragma unroll
        for (int i = 0; i < 4; ++i) {
            int f = tid + 256 * i;
            int ss = f >> 4, d4 = (f & 15) << 2;
            float4 v = *(const float4*)(vb + (size_t)(s0 + ss) * (cH * cD) + d4);
            vT[ss][d4+0] = v.x; vT[ss][d4+1] = v.y; vT[ss][d4+2] = v.z; vT[ss][d4+3] = v.w;
        }
        __syncthreads();
        for (int ss = 0; ss < 64; ++ss) {
            float pv[4];
#pragma unroll
            for (int i = 0; i < 4; ++i) pv[i] = pT[ty + 16 * i][ss];
            float4 vv = *(const float4*)&vT[ss][tx * 4];
#pragma unroll
            for (int i = 0; i < 4; ++i) {
                acc[i][0] = fmaf(pv[i], vv.x, acc[i][0]);
                acc[i][1] = fmaf(pv[i], vv.y, acc[i][1]);
                acc[i][2] = fmaf(pv[i], vv.z, acc[i][2]);
                acc[i][3] = fmaf(pv[i], vv.w, acc[i][3]);
            }
        }
        __syncthreads();
    }
    float* dst = part + (((size_t)sk * cNH + nh) * cC + ch * 64) * cD;
#pragma unroll
    for (int i = 0; i < 4; ++i) {
        float4 o; o.x = acc[i][0]; o.y = acc[i][1]; o.z = acc[i][2]; o.w = acc[i][3];
        *(float4*)(dst + (size_t)(ty + 16 * i) * cD + tx * 4) = o;
    }
}

// ---------------- Kernel 4d: reduce split-K partials ---------------------
__global__ __launch_bounds__(256)
void k_red(const float* __restrict__ part, float* __restrict__ vbg)
{
    int i = blockIdx.x * 256 + threadIdx.x;      // over 16*128*64 = 131072
    float acc = 0.f;
    for (int sk = 0; sk < SK; ++sk) acc += part[(size_t)sk * (cNH * cC * cD) + i];
    vbg[i] = acc;
}

// ---------------- Kernel 5: per-query epilogue ---------------------------
// one wave (64 lanes) per query, 4 waves per block
__global__ __launch_bounds__(256)
void k_out(const float* __restrict__ q, const float* __restrict__ key,
           const float* __restrict__ val, const int* __restrict__ cl,
           const float* __restrict__ abk, const float* __restrict__ vbg,
           const int* __restrict__ topk, float* __restrict__ out)
{
    __shared__ float klds[4][cK][cE + 2];
    __shared__ float qlds[4][cE];
    __shared__ float qks[4][cK];
    __shared__ int   st[4][cK];
    int tid = threadIdx.x, lane = tid & 63, wid = tid >> 6;
    int qidx = blockIdx.x * 4 + wid;        // (n*H + h)*L + l
    int l = qidx % cL, nh = qidx / cL;
    int h = nh % cH, n = nh / cH;
    int c = cl[qidx];
    const int* tk = topk + ((size_t)nh * cC + c) * cK;
    if (lane < cK) st[wid][lane] = tk[lane];
    qlds[wid][lane] = q[(((size_t)n * cL + l) * cH + h) * cE + lane];
    __syncthreads();
    const float* kb = key + ((size_t)n * cS * cH + h) * cE;
    for (int j = 0; j < cK; ++j) {
        int t = st[wid][j];
        klds[wid][j][lane] = kb[(size_t)t * cH * cE + lane];
    }
    __syncthreads();
    if (lane < cK) {
        float acc = 0.f;
#pragma unroll
        for (int e = 0; e < cE; ++e)
            acc = fmaf(qlds[wid][e], klds[wid][lane][e], acc);
        qks[wid][lane] = acc;
    }
    __syncthreads();
    float m = -INFINITY;
#pragma unroll
    for (int j = 0; j < cK; ++j) m = fmaxf(m, qks[wid][j]);
    float den = 0.f;
    float ev[cK];
#pragma unroll
    for (int j = 0; j < cK; ++j) { float e = expf(0.125f * (qks[wid][j] - m)); ev[j] = e; den += e; }
    float scale = 1.0f - abk[(size_t)nh * cC + c];
#pragma unroll
    for (int j = 0; j < cK; ++j) ev[j] = (ev[j] / den) * scale;   // A_s
    const float* vb = val + ((size_t)n * cS * cH + h) * cD + lane;
    float acc = 0.f;
#pragma unroll
    for (int j = 0; j < cK; ++j) {
        int t = st[wid][j];
        acc = fmaf(ev[j], vb[(size_t)t * cH * cD], acc);
    }
    acc += vbg[((size_t)nh * cC + c) * cD + lane];
    out[(((size_t)n * cL + l) * cH + h) * cD + lane] = acc;       // (N,L,H,D)
    const size_t off1 = (size_t)cN * cL * cH * cD;
    const size_t off2 = off1 + (size_t)cN * cH * cL * cK;
    if (lane < cK) {
        out[off1 + (size_t)qidx * cK + lane] = (float)st[wid][lane];  // sparse_index
        out[off2 + (size_t)qidx * cK + lane] = ev[lane];              // A_topk
    }
}

// ---------------- launch -------------------------------------------------
extern "C" void kernel_launch(void* const* d_in, const int* in_sizes, int n_in,
                              void* d_out, int out_size, void* d_ws, size_t ws_size,
                              hipStream_t stream)
{
    (void)in_sizes; (void)n_in; (void)out_size; (void)ws_size;
    const float* q      = (const float*)d_in[0];
    const float* key    = (const float*)d_in[1];
    const float* val    = (const float*)d_in[2];
    const float* planes = (const float*)d_in[3];
    char* w = (char*)d_ws;
    unsigned int* bits = (unsigned int*)w;  w += (size_t)cN * cH * cL * 4;
    int*   cl     = (int*)w;                w += (size_t)cN * cH * cL * 4;
    int*   counts = (int*)w;                w += (size_t)cN * cH * cC * 4;
    float* abk    = (float*)w;              w += (size_t)cN * cH * cC * 4;
    float* Qg     = (float*)w;              w += (size_t)cN * cH * cC * cE * 4;
    float* vbg    = (float*)w;              w += (size_t)cN * cH * cC * cD * 4;
    int*   topkp  = (int*)w;                w += (size_t)cN * cH * cC * cK * 4;
    float* QK     = (float*)w;              w += (size_t)cNH * cC * cS * 4;      // 16 MB (QK -> P in place)
    float* part   = (float*)w;              w += (size_t)SK * cNH * cC * cD * 4; // 4 MB
    unsigned int* cent = (unsigned int*)w;  w += (size_t)cNH * cC * 4;           // 8 KB
    int*   partial = (int*)w;               w += (size_t)cNH * TILES * HW * 4;   // 2.2 MB
    float* out = (float*)d_out;

    k_bits   <<<(cN * cH * cL) / 256, 256, 0, stream>>>(q, planes, bits);
    k_init   <<<(cNH * cC) / 256, 256, 0, stream>>>(bits, cent);
    for (int it = 0; it < cIT; ++it) {
        k_assign <<<cNH * TILES, 256, 0, stream>>>(bits, cent, partial, cl, 0);
        k_update <<<cNH, 128, 0, stream>>>(partial, cent, counts, 0);
    }
    k_assign <<<cNH * TILES, 256, 0, stream>>>(bits, cent, partial, cl, 1);
    k_update <<<cNH, 128, 0, stream>>>(partial, cent, counts, 1);
    k_qg     <<<cNH * CG, 256, 0, stream>>>(q, cl, counts, Qg);
    k_qk_gemm<<<cNH * 16, 256, 0, stream>>>(key, Qg, QK);
    k_sel    <<<cNH * cC, 256, 0, stream>>>(QK, topkp, abk);
    k_pv     <<<cNH * SK * 2, 256, 0, stream>>>(QK, val, part);
    k_red    <<<(cNH * cC * cD) / 256, 256, 0, stream>>>(part, vbg);
    k_out    <<<(cN * cH * cL) / 4, 256, 0, stream>>>(q, key, val, cl, abk, vbg, topkp, out);
}

// Round 6
// 519.334 us; speedup vs baseline: 1.2785x; 1.0325x over previous
//
#include <hip/hip_runtime.h>
#include <math.h>

constexpr int cN = 2, cH = 8, cL = 2048, cS = 2048, cE = 64, cD = 64;
constexpr int cC = 128, cK = 32, cB = 32, cIT = 10;
constexpr int cNH = cN * cH;          // 16
constexpr int SK = 8;                 // split-K factor for PV
constexpr int CHUNK = cS / SK;        // 256 s per split
constexpr int TILES = 8;              // point tiles per nh in k_assign
constexpr int HW = cC * 33;           // partial hist words: sbs[128][32] + scnt[128]
// TEMP = 1/sqrt(64) = 0.125 exactly

// ---------------- Kernel 1: LSH bits -------------------------------------
__global__ __launch_bounds__(256)
void k_bits(const float* __restrict__ q, const float* __restrict__ planes,
            unsigned int* __restrict__ bits)
{
    __shared__ float pl[cB * (cE + 1)];
    int tid = threadIdx.x;
    for (int i = tid; i < cB * (cE + 1); i += 256) pl[i] = planes[i];
    __syncthreads();
    int idx = blockIdx.x * 256 + tid;           // (n*H + h)*L + l
    int l = idx % cL, h = (idx / cL) % cH, n = idx / (cL * cH);
    const float* qr = q + (((size_t)n * cL + l) * cH + h) * cE;
    float qv[cE];
#pragma unroll
    for (int e4 = 0; e4 < cE / 4; ++e4) {
        float4 f = ((const float4*)qr)[e4];
        qv[4*e4+0] = f.x; qv[4*e4+1] = f.y; qv[4*e4+2] = f.z; qv[4*e4+3] = f.w;
    }
    unsigned int w = 0;
    for (int b = 0; b < cB; ++b) {
        float acc = 0.f;
#pragma unroll
        for (int e = 0; e < cE; ++e) acc = fmaf(qv[e], pl[b * (cE + 1) + e], acc);
        acc += pl[b * (cE + 1) + cE];
        if (acc > 0.f) w |= (1u << b);
    }
    bits[idx] = w;
}

// ---------------- Kernel 2a: initial centroids ---------------------------
__global__ __launch_bounds__(256)
void k_init(const unsigned int* __restrict__ bits, unsigned int* __restrict__ cent)
{
    int i = blockIdx.x * 256 + threadIdx.x;     // nh*128 + c
    int c = i & 127, nh = i >> 7;
    // idx0 = linspace(0, L-1, C).astype(int32): floor(c*2047/127), endpoint exact
    int i0 = (int)(((double)c * 2047.0) / 127.0);
    cent[i] = bits[(size_t)nh * cL + i0];
}

// ---------------- Kernel 2b: assignment + partial histograms -------------
// grid = 16 nh x 8 tiles = 128 blocks, 256 threads (1 point each)
__global__ __launch_bounds__(256)
void k_assign(const unsigned int* __restrict__ bits,
              const unsigned int* __restrict__ cent,
              int* __restrict__ partial, int* __restrict__ cl, int write_cl)
{
    __shared__ unsigned int scb[cC] __attribute__((aligned(16)));
    __shared__ int hist[HW];      // [c*32+b] bitsums, [4096+c] counts
    int tid = threadIdx.x;
    int lane = tid & 63;
    int tile = blockIdx.x & (TILES - 1), nh = blockIdx.x / TILES;
    if (tid < cC) scb[tid] = cent[nh * cC + tid];
    for (int i = tid; i < HW; i += 256) hist[i] = 0;
    int l = tile * 256 + tid;
    unsigned int w = bits[(size_t)nh * cL + l];
    // per-lane bit ballots over this wave's 64 points (lane b&31 keeps bit b)
    unsigned long long mymb = 0ull;
#pragma unroll
    for (int b = 0; b < cB; ++b) {
        unsigned long long m = __ballot((w >> b) & 1u);
        if ((lane & 31) == b) mymb = m;
    }
    __syncthreads();
    const uint4* scb4 = (const uint4*)scb;
    // packed key = (hamming<<8)|c -> min = lowest dist, tie lowest c
    int best = 0x7fffffff;
    for (int c4 = 0; c4 < cC / 4; ++c4) {
        uint4 cb = scb4[c4];
        int c = c4 * 4;
        best = min(best, (__popc(w ^ cb.x) << 8) | c);
        best = min(best, (__popc(w ^ cb.y) << 8) | (c + 1));
        best = min(best, (__popc(w ^ cb.z) << 8) | (c + 2));
        best = min(best, (__popc(w ^ cb.w) << 8) | (c + 3));
    }
    int bc = best & 255;
    if (write_cl) cl[(size_t)nh * cL + l] = bc;
    // wave-aggregated histogram into LDS (integer atomics: deterministic)
    for (int c = 0; c < cC; ++c) {
        unsigned long long m = __ballot(bc == c);
        if (m) {
            if (lane < cB) {
                int contrib = __popcll(m & mymb);
                if (contrib) atomicAdd(&hist[c * 32 + lane], contrib);
            }
            if (lane == 63) atomicAdd(&hist[4096 + c], __popcll(m));
        }
    }
    __syncthreads();
    int* dst = partial + (size_t)(nh * TILES + tile) * HW;
    for (int i = tid; i < HW; i += 256) dst[i] = hist[i];
}

// ---------------- Kernel 2c: centroid update / final counts --------------
// grid = 16 blocks x 128 threads (thread = cluster)
__global__ __launch_bounds__(128)
void k_update(const int* __restrict__ partial, unsigned int* __restrict__ cent,
              int* __restrict__ counts, int mode)
{
    int c = threadIdx.x, nh = blockIdx.x;
    int cnt = 0;
    int bs[cB];
#pragma unroll
    for (int b = 0; b < cB; ++b) bs[b] = 0;
    for (int t = 0; t < TILES; ++t) {
        const int* p = partial + (size_t)(nh * TILES + t) * HW;
        cnt += p[4096 + c];
#pragma unroll
        for (int b = 0; b < cB; ++b) bs[b] += p[c * 32 + b];
    }
    if (mode == 0) {
        if (cnt > 0) {                       // keep old centroid if empty
            unsigned int nw = 0;
#pragma unroll
            for (int b = 0; b < cB; ++b)
                if (2 * bs[b] > cnt) nw |= (1u << b);
            cent[nh * cC + c] = nw;
        }
    } else {
        counts[nh * cC + c] = cnt;
    }
}

// ---------------- Kernel 2d: counting-sort member lists ------------------
// grid = 16 blocks (nh) x 128 threads (thread = cluster); stable, ascending l
__global__ __launch_bounds__(128)
void k_gather(const int* __restrict__ cl, const int* __restrict__ counts,
              int* __restrict__ mlist, int* __restrict__ moff)
{
    __shared__ int scl[cL] __attribute__((aligned(16)));
    __shared__ int soff[cC];
    int tid = threadIdx.x, nh = blockIdx.x;
    const int* clr = cl + (size_t)nh * cL;
    for (int i = tid; i < cL; i += 128) scl[i] = clr[i];
    if (tid == 0) {
        int run = 0;
        for (int c = 0; c < cC; ++c) { soff[c] = run; run += counts[nh * cC + c]; }
    }
    __syncthreads();
    int c = tid;
    int cur = soff[c];
    moff[nh * cC + c] = cur;
    int* dst = mlist + (size_t)nh * cL;
    const int4* scl4 = (const int4*)scl;
    for (int l4 = 0; l4 < cL / 4; ++l4) {
        int4 v = scl4[l4];                 // LDS broadcast read
        int l = l4 * 4;
        if (v.x == c) dst[cur++] = l;
        if (v.y == c) dst[cur++] = l + 1;
        if (v.z == c) dst[cur++] = l + 2;
        if (v.w == c) dst[cur++] = l + 3;
    }
}

// ---------------- Kernel 3: cluster-mean queries Qg ----------------------
// one block (64 lanes = e) per (nh,c); dense member list, batched loads,
// strict ascending-l single-accumulator chain (bit-exact vs np GEMM)
__global__ __launch_bounds__(64)
void k_qg(const float* __restrict__ q, const int* __restrict__ mlist,
          const int* __restrict__ moff, const int* __restrict__ counts,
          float* __restrict__ Qg)
{
    int b = blockIdx.x;                 // nh*cC + c
    int c = b & 127, nh = b >> 7; (void)c;
    int h = nh % cH, n = nh / cH;
    int lane = threadIdx.x;
    int off = moff[b];
    int cnt = counts[b];
    const int* ml = mlist + (size_t)nh * cL + off;
    const float* qb = q + ((size_t)n * cL * cH + h) * cE + lane;
    float acc = 0.f;
    int j = 0;
    for (; j + 4 <= cnt; j += 4) {
        int i0 = ml[j], i1 = ml[j + 1], i2 = ml[j + 2], i3 = ml[j + 3];
        float v0 = qb[(size_t)i0 * cH * cE];
        float v1 = qb[(size_t)i1 * cH * cE];
        float v2 = qb[(size_t)i2 * cH * cE];
        float v3 = qb[(size_t)i3 * cH * cE];
        acc += v0; acc += v1; acc += v2; acc += v3;    // in-order chain
    }
    for (; j < cnt; ++j) acc += qb[(size_t)ml[j] * cH * cE];
    float cs = (float)(cnt > 0 ? cnt : 1);
    Qg[(size_t)b * cE + lane] = acc / cs;
}

// ---------------- Kernel 4a: QK = Qg . k^T  (tiled GEMM, exact chains) ---
// grid = nh(16) x s-tiles(16 of 128); block 256 = 16 ty (c) x 16 tx (s)
__global__ __launch_bounds__(256)
void k_qk_gemm(const float* __restrict__ key, const float* __restrict__ Qg,
               float* __restrict__ QK)
{
    __shared__ float qgT[cE][cC + 2];      // [e][c]
    __shared__ float kT[cE][128 + 2];      // [e][s_local]
    int tid = threadIdx.x;
    int bs = blockIdx.x & 15;              // s-tile
    int nh = blockIdx.x >> 4;
    int h = nh % cH, n = nh / cH;
    const float4* qsrc = (const float4*)(Qg + (size_t)nh * cC * cE);
#pragma unroll
    for (int i = 0; i < 8; ++i) {
        int f = tid + 256 * i;
        int c = f >> 4, e4 = (f & 15) << 2;
        float4 v = qsrc[f];
        qgT[e4+0][c] = v.x; qgT[e4+1][c] = v.y; qgT[e4+2][c] = v.z; qgT[e4+3][c] = v.w;
    }
    const float* kb = key + (size_t)n * cS * cH * cE + (size_t)h * cE;
    int s0 = bs * 128;
#pragma unroll
    for (int i = 0; i < 8; ++i) {
        int f = tid + 256 * i;
        int s = f >> 4, e4 = (f & 15) << 2;
        float4 v = *(const float4*)(kb + (size_t)(s0 + s) * (cH * cE) + e4);
        kT[e4+0][s] = v.x; kT[e4+1][s] = v.y; kT[e4+2][s] = v.z; kT[e4+3][s] = v.w;
    }
    __syncthreads();
    int tx = tid & 15, ty = tid >> 4;
    float acc[8][8];
#pragma unroll
    for (int i = 0; i < 8; ++i)
#pragma unroll
        for (int j = 0; j < 8; ++j) acc[i][j] = 0.f;
    for (int e = 0; e < cE; ++e) {
        float qv[8], kv[8];
#pragma unroll
        for (int i = 0; i < 8; ++i) qv[i] = qgT[e][ty + 16 * i];
#pragma unroll
        for (int j = 0; j < 8; ++j) kv[j] = kT[e][tx + 16 * j];
#pragma unroll
        for (int i = 0; i < 8; ++i)
#pragma unroll
            for (int j = 0; j < 8; ++j)
                acc[i][j] = fmaf(qv[i], kv[j], acc[i][j]);   // ascending-e chain
    }
    float* dst = QK + (size_t)nh * cC * cS + s0;
#pragma unroll
    for (int i = 0; i < 8; ++i)
#pragma unroll
        for (int j = 0; j < 8; ++j)
            dst[(size_t)(ty + 16 * i) * cS + tx + 16 * j] = acc[i][j];
}

// ---------------- Kernel 4b: per-row top-32 + softmax -> P (in-place) ----
// one block (256 threads) per (n,h,c) row
__global__ __launch_bounds__(256)
void k_sel(float* __restrict__ QK, int* __restrict__ topk,
           float* __restrict__ abk)
{
    __shared__ float row[cS];
    __shared__ float work[cS];
    __shared__ float rv[4];
    __shared__ int   ri[4];
    __shared__ int   stopk[cK];
    __shared__ float sM, sDen;
    int tid = threadIdx.x;
    int lane = tid & 63, wid = tid >> 6;
    int b = blockIdx.x;                 // (n*H + h)*C + c
    float* qrow = QK + (size_t)b * cS;
    for (int j = 0; j < cS / 256; ++j) {
        int s = tid + j * 256;
        float v = qrow[s];
        row[s] = v; work[s] = v;
    }
    __syncthreads();
    // iterative top-32, tie -> lower index (jax.lax.top_k semantics)
    for (int itk = 0; itk < cK; ++itk) {
        float bv = -INFINITY; int bi = 0x7fffffff;
        for (int j = 0; j < cS / 256; ++j) {
            int s = tid + j * 256;
            float v = work[s];
            if (v > bv) { bv = v; bi = s; }
        }
#pragma unroll
        for (int off = 32; off; off >>= 1) {
            float ov = __shfl_xor(bv, off);
            int   oi = __shfl_xor(bi, off);
            if (ov > bv || (ov == bv && oi < bi)) { bv = ov; bi = oi; }
        }
        if (lane == 0) { rv[wid] = bv; ri[wid] = bi; }
        __syncthreads();
        if (tid == 0) {
            float v = rv[0]; int i = ri[0];
            for (int wv = 1; wv < 4; ++wv)
                if (rv[wv] > v || (rv[wv] == v && ri[wv] < i)) { v = rv[wv]; i = ri[wv]; }
            stopk[itk] = i;
            work[i] = -INFINITY;
        }
        __syncthreads();
    }
    if (tid < cK) topk[(size_t)b * cK + tid] = stopk[tid];
    // softmax over full row (TEMP=0.125 scaling exact; shift by max)
    float mv = -INFINITY;
    for (int j = 0; j < cS / 256; ++j) mv = fmaxf(mv, row[tid + j * 256]);
#pragma unroll
    for (int off = 32; off; off >>= 1) mv = fmaxf(mv, __shfl_xor(mv, off));
    if (lane == 0) rv[wid] = mv;
    __syncthreads();
    if (tid == 0) sM = fmaxf(fmaxf(rv[0], rv[1]), fmaxf(rv[2], rv[3]));
    __syncthreads();
    float M = sM;
    float psum = 0.f;
    for (int j = 0; j < cS / 256; ++j) {
        int s = tid + j * 256;
        float e = expf(0.125f * (row[s] - M));
        work[s] = e;
        psum += e;
    }
#pragma unroll
    for (int off = 32; off; off >>= 1) psum += __shfl_xor(psum, off);
    if (lane == 0) rv[wid] = psum;
    __syncthreads();
    if (tid == 0) sDen = ((rv[0] + rv[1]) + rv[2]) + rv[3];
    __syncthreads();
    float den = sDen;
    for (int j = 0; j < cS / 256; ++j) { int s = tid + j * 256; work[s] = work[s] / den; }
    __syncthreads();
    if (tid < cK) work[stopk[tid]] = 0.f;        // mask out top-k
    __syncthreads();
    // A_bottomk
    float ps = 0.f;
    for (int j = 0; j < cS / 256; ++j) ps += work[tid + j * 256];
#pragma unroll
    for (int off = 32; off; off >>= 1) ps += __shfl_xor(ps, off);
    if (lane == 0) rv[wid] = ps;
    __syncthreads();
    if (tid == 0) abk[b] = ((rv[0] + rv[1]) + rv[2]) + rv[3];
    // write P back in place (normalized, top-k zeroed)
    for (int j = 0; j < cS / 256; ++j) { int s = tid + j * 256; qrow[s] = work[s]; }
}

// ---------------- Kernel 4c: Vb_g partials = P . v (split-K GEMM) --------
// grid = nh(16) x sk(8) x ch(2);  block 256 = 16 ty (c) x 16 tx (d4)
__global__ __launch_bounds__(256)
void k_pv(const float* __restrict__ P, const float* __restrict__ val,
          float* __restrict__ part)
{
    __shared__ float pT[64][64 + 2];       // [c_local][s_sub]
    __shared__ float vT[64][cD + 4];       // [s_sub][d]
    int tid = threadIdx.x;
    int ch = blockIdx.x & 1;
    int sk = (blockIdx.x >> 1) & 7;
    int nh = blockIdx.x >> 4;
    int h = nh % cH, n = nh / cH;
    int tx = tid & 15, ty = tid >> 4;
    float acc[4][4];
#pragma unroll
    for (int i = 0; i < 4; ++i)
#pragma unroll
        for (int j = 0; j < 4; ++j) acc[i][j] = 0.f;
    const float* pb = P + ((size_t)nh * cC + ch * 64) * cS;
    const float* vb = val + (size_t)n * cS * cH * cD + (size_t)h * cD;
    for (int sub = 0; sub < CHUNK / 64; ++sub) {
        int s0 = sk * CHUNK + sub * 64;
#pragma unroll
        for (int i = 0; i < 4; ++i) {
            int f = tid + 256 * i;
            int c = f >> 4, s4 = (f & 15) << 2;
            float4 v = *(const float4*)(pb + (size_t)c * cS + s0 + s4);
            pT[c][s4+0] = v.x; pT[c][s4+1] = v.y; pT[c][s4+2] = v.z; pT[c][s4+3] = v.w;
        }
#pragma unroll
        for (int i = 0; i < 4; ++i) {
            int f = tid + 256 * i;
            int ss = f >> 4, d4 = (f & 15) << 2;
            float4 v = *(const float4*)(vb + (size_t)(s0 + ss) * (cH * cD) + d4);
            vT[ss][d4+0] = v.x; vT[ss][d4+1] = v.y; vT[ss][d4+2] = v.z; vT[ss][d4+3] = v.w;
        }
        __syncthreads();
        for (int ss = 0; ss < 64; ++ss) {
            float pv[4];
#pragma unroll
            for (int i = 0; i < 4; ++i) pv[i] = pT[ty + 16 * i][ss];
            float4 vv = *(const float4*)&vT[ss][tx * 4];
#pragma unroll
            for (int i = 0; i < 4; ++i) {
                acc[i][0] = fmaf(pv[i], vv.x, acc[i][0]);
                acc[i][1] = fmaf(pv[i], vv.y, acc[i][1]);
                acc[i][2] = fmaf(pv[i], vv.z, acc[i][2]);
                acc[i][3] = fmaf(pv[i], vv.w, acc[i][3]);
            }
        }
        __syncthreads();
    }
    float* dst = part + (((size_t)sk * cNH + nh) * cC + ch * 64) * cD;
#pragma unroll
    for (int i = 0; i < 4; ++i) {
        float4 o; o.x = acc[i][0]; o.y = acc[i][1]; o.z = acc[i][2]; o.w = acc[i][3];
        *(float4*)(dst + (size_t)(ty + 16 * i) * cD + tx * 4) = o;
    }
}

// ---------------- Kernel 4d: reduce split-K partials ---------------------
__global__ __launch_bounds__(256)
void k_red(const float* __restrict__ part, float* __restrict__ vbg)
{
    int i = blockIdx.x * 256 + threadIdx.x;      // over 16*128*64 = 131072
    float acc = 0.f;
    for (int sk = 0; sk < SK; ++sk) acc += part[(size_t)sk * (cNH * cC * cD) + i];
    vbg[i] = acc;
}

// ---------------- Kernel 5: per-query epilogue ---------------------------
// one wave (64 lanes) per query, 4 waves per block
__global__ __launch_bounds__(256)
void k_out(const float* __restrict__ q, const float* __restrict__ key,
           const float* __restrict__ val, const int* __restrict__ cl,
           const float* __restrict__ abk, const float* __restrict__ vbg,
           const int* __restrict__ topk, float* __restrict__ out)
{
    __shared__ float klds[4][cK][cE + 2];
    __shared__ float qlds[4][cE];
    __shared__ float qks[4][cK];
    __shared__ int   st[4][cK];
    int tid = threadIdx.x, lane = tid & 63, wid = tid >> 6;
    int qidx = blockIdx.x * 4 + wid;        // (n*H + h)*L + l
    int l = qidx % cL, nh = qidx / cL;
    int h = nh % cH, n = nh / cH;
    int c = cl[qidx];
    const int* tk = topk + ((size_t)nh * cC + c) * cK;
    if (lane < cK) st[wid][lane] = tk[lane];
    qlds[wid][lane] = q[(((size_t)n * cL + l) * cH + h) * cE + lane];
    __syncthreads();
    const float* kb = key + ((size_t)n * cS * cH + h) * cE;
    for (int j = 0; j < cK; ++j) {
        int t = st[wid][j];
        klds[wid][j][lane] = kb[(size_t)t * cH * cE + lane];
    }
    __syncthreads();
    if (lane < cK) {
        float acc = 0.f;
#pragma unroll
        for (int e = 0; e < cE; ++e)
            acc = fmaf(qlds[wid][e], klds[wid][lane][e], acc);
        qks[wid][lane] = acc;
    }
    __syncthreads();
    float m = -INFINITY;
#pragma unroll
    for (int j = 0; j < cK; ++j) m = fmaxf(m, qks[wid][j]);
    float den = 0.f;
    float ev[cK];
#pragma unroll
    for (int j = 0; j < cK; ++j) { float e = expf(0.125f * (qks[wid][j] - m)); ev[j] = e; den += e; }
    float scale = 1.0f - abk[(size_t)nh * cC + c];
#pragma unroll
    for (int j = 0; j < cK; ++j) ev[j] = (ev[j] / den) * scale;   // A_s
    const float* vb = val + ((size_t)n * cS * cH + h) * cD + lane;
    float acc = 0.f;
#pragma unroll
    for (int j = 0; j < cK; ++j) {
        int t = st[wid][j];
        acc = fmaf(ev[j], vb[(size_t)t * cH * cD], acc);
    }
    acc += vbg[((size_t)nh * cC + c) * cD + lane];
    out[(((size_t)n * cL + l) * cH + h) * cD + lane] = acc;       // (N,L,H,D)
    const size_t off1 = (size_t)cN * cL * cH * cD;
    const size_t off2 = off1 + (size_t)cN * cH * cL * cK;
    if (lane < cK) {
        out[off1 + (size_t)qidx * cK + lane] = (float)st[wid][lane];  // sparse_index
        out[off2 + (size_t)qidx * cK + lane] = ev[lane];              // A_topk
    }
}

// ---------------- launch -------------------------------------------------
extern "C" void kernel_launch(void* const* d_in, const int* in_sizes, int n_in,
                              void* d_out, int out_size, void* d_ws, size_t ws_size,
                              hipStream_t stream)
{
    (void)in_sizes; (void)n_in; (void)out_size; (void)ws_size;
    const float* q      = (const float*)d_in[0];
    const float* key    = (const float*)d_in[1];
    const float* val    = (const float*)d_in[2];
    const float* planes = (const float*)d_in[3];
    char* w = (char*)d_ws;
    unsigned int* bits = (unsigned int*)w;  w += (size_t)cN * cH * cL * 4;
    int*   cl     = (int*)w;                w += (size_t)cN * cH * cL * 4;
    int*   counts = (int*)w;                w += (size_t)cN * cH * cC * 4;
    float* abk    = (float*)w;              w += (size_t)cN * cH * cC * 4;
    float* Qg     = (float*)w;              w += (size_t)cN * cH * cC * cE * 4;
    float* vbg    = (float*)w;              w += (size_t)cN * cH * cC * cD * 4;
    int*   topkp  = (int*)w;                w += (size_t)cN * cH * cC * cK * 4;
    float* QK     = (float*)w;              w += (size_t)cNH * cC * cS * 4;      // 16 MB (QK -> P in place)
    float* part   = (float*)w;              w += (size_t)SK * cNH * cC * cD * 4; // 4 MB
    unsigned int* cent = (unsigned int*)w;  w += (size_t)cNH * cC * 4;           // 8 KB
    int*   partial = (int*)w;               w += (size_t)cNH * TILES * HW * 4;   // 2.2 MB
    int*   mlist  = (int*)w;                w += (size_t)cNH * cL * 4;           // 128 KB
    int*   moff   = (int*)w;                w += (size_t)cNH * cC * 4;           // 8 KB
    float* out = (float*)d_out;

    k_bits   <<<(cN * cH * cL) / 256, 256, 0, stream>>>(q, planes, bits);
    k_init   <<<(cNH * cC) / 256, 256, 0, stream>>>(bits, cent);
    for (int it = 0; it < cIT; ++it) {
        k_assign <<<cNH * TILES, 256, 0, stream>>>(bits, cent, partial, cl, 0);
        k_update <<<cNH, 128, 0, stream>>>(partial, cent, counts, 0);
    }
    k_assign <<<cNH * TILES, 256, 0, stream>>>(bits, cent, partial, cl, 1);
    k_update <<<cNH, 128, 0, stream>>>(partial, cent, counts, 1);
    k_gather <<<cNH, 128, 0, stream>>>(cl, counts, mlist, moff);
    k_qg     <<<cNH * cC, 64, 0, stream>>>(q, mlist, moff, counts, Qg);
    k_qk_gemm<<<cNH * 16, 256, 0, stream>>>(key, Qg, QK);
    k_sel    <<<cNH * cC, 256, 0, stream>>>(QK, topkp, abk);
    k_pv     <<<cNH * SK * 2, 256, 0, stream>>>(QK, val, part);
    k_red    <<<(cNH * cC * cD) / 256, 256, 0, stream>>>(part, vbg);
    k_out    <<<(cN * cH * cL) / 4, 256, 0, stream>>>(q, key, val, cl, abk, vbg, topkp, out);
}

// Round 7
// 447.101 us; speedup vs baseline: 1.4851x; 1.1616x over previous
//
#include <hip/hip_runtime.h>
#include <math.h>

constexpr int cN = 2, cH = 8, cL = 2048, cS = 2048, cE = 64, cD = 64;
constexpr int cC = 128, cK = 32, cB = 32, cIT = 10;
constexpr int cNH = cN * cH;          // 16
constexpr int SK = 8;                 // split-K factor for PV
constexpr int CHUNK = cS / SK;        // 256 s per split
constexpr int TILES = 8;              // point tiles per nh in k_assign
constexpr int HW = cC * 33;           // partial hist words: sbs[128][32] + scnt[128]
// TEMP = 1/sqrt(64) = 0.125 exactly

// ---------------- Kernel 1: LSH bits -------------------------------------
__global__ __launch_bounds__(256)
void k_bits(const float* __restrict__ q, const float* __restrict__ planes,
            unsigned int* __restrict__ bits)
{
    __shared__ float pl[cB * (cE + 1)];
    int tid = threadIdx.x;
    for (int i = tid; i < cB * (cE + 1); i += 256) pl[i] = planes[i];
    __syncthreads();
    int idx = blockIdx.x * 256 + tid;           // (n*H + h)*L + l
    int l = idx % cL, h = (idx / cL) % cH, n = idx / (cL * cH);
    const float* qr = q + (((size_t)n * cL + l) * cH + h) * cE;
    float qv[cE];
#pragma unroll
    for (int e4 = 0; e4 < cE / 4; ++e4) {
        float4 f = ((const float4*)qr)[e4];
        qv[4*e4+0] = f.x; qv[4*e4+1] = f.y; qv[4*e4+2] = f.z; qv[4*e4+3] = f.w;
    }
    unsigned int w = 0;
    for (int b = 0; b < cB; ++b) {
        float acc = 0.f;
#pragma unroll
        for (int e = 0; e < cE; ++e) acc = fmaf(qv[e], pl[b * (cE + 1) + e], acc);
        acc += pl[b * (cE + 1) + cE];
        if (acc > 0.f) w |= (1u << b);
    }
    bits[idx] = w;
}

// ---------------- Kernel 2a: initial centroids ---------------------------
__global__ __launch_bounds__(256)
void k_init(const unsigned int* __restrict__ bits, unsigned int* __restrict__ cent)
{
    int i = blockIdx.x * 256 + threadIdx.x;     // nh*128 + c
    int c = i & 127, nh = i >> 7;
    // idx0 = linspace(0, L-1, C).astype(int32): floor(i*2047/127), endpoint exact
    int i0 = (int)(((double)c * 2047.0) / 127.0);
    cent[i] = bits[(size_t)nh * cL + i0];
}

// ---------------- Kernel 2b: assignment + partial histograms -------------
// grid = 16 nh x 8 tiles = 128 blocks, 256 threads (1 point each)
__global__ __launch_bounds__(256)
void k_assign(const unsigned int* __restrict__ bits,
              const unsigned int* __restrict__ cent,
              int* __restrict__ partial, int* __restrict__ cl, int write_cl)
{
    __shared__ unsigned int scb[cC] __attribute__((aligned(16)));
    __shared__ int hist[HW];      // [c*32+b] bitsums, [4096+c] counts
    int tid = threadIdx.x;
    int lane = tid & 63;
    int tile = blockIdx.x & (TILES - 1), nh = blockIdx.x / TILES;
    if (tid < cC) scb[tid] = cent[nh * cC + tid];
    for (int i = tid; i < HW; i += 256) hist[i] = 0;
    int l = tile * 256 + tid;
    unsigned int w = bits[(size_t)nh * cL + l];
    // per-lane bit ballots over this wave's 64 points (lane b&31 keeps bit b)
    unsigned long long mymb = 0ull;
#pragma unroll
    for (int b = 0; b < cB; ++b) {
        unsigned long long m = __ballot((w >> b) & 1u);
        if ((lane & 31) == b) mymb = m;
    }
    __syncthreads();
    const uint4* scb4 = (const uint4*)scb;
    // packed key = (hamming<<8)|c -> min = lowest dist, tie lowest c
    int best = 0x7fffffff;
    for (int c4 = 0; c4 < cC / 4; ++c4) {
        uint4 cb = scb4[c4];
        int c = c4 * 4;
        best = min(best, (__popc(w ^ cb.x) << 8) | c);
        best = min(best, (__popc(w ^ cb.y) << 8) | (c + 1));
        best = min(best, (__popc(w ^ cb.z) << 8) | (c + 2));
        best = min(best, (__popc(w ^ cb.w) << 8) | (c + 3));
    }
    int bc = best & 255;
    if (write_cl) cl[(size_t)nh * cL + l] = bc;
    // wave-aggregated histogram into LDS (integer atomics: deterministic)
    for (int c = 0; c < cC; ++c) {
        unsigned long long m = __ballot(bc == c);
        if (m) {
            if (lane < cB) {
                int contrib = __popcll(m & mymb);
                if (contrib) atomicAdd(&hist[c * 32 + lane], contrib);
            }
            if (lane == 63) atomicAdd(&hist[4096 + c], __popcll(m));
        }
    }
    __syncthreads();
    int* dst = partial + (size_t)(nh * TILES + tile) * HW;
    for (int i = tid; i < HW; i += 256) dst[i] = hist[i];
}

// ---------------- Kernel 2c: centroid update / final counts+moff ---------
// grid = 16 blocks x 128 threads (thread = cluster)
__global__ __launch_bounds__(128)
void k_update(const int* __restrict__ partial, unsigned int* __restrict__ cent,
              int* __restrict__ counts, int* __restrict__ moff, int mode)
{
    __shared__ int scn[cC];
    int c = threadIdx.x, nh = blockIdx.x;
    int cnt = 0;
    int bs[cB];
#pragma unroll
    for (int b = 0; b < cB; ++b) bs[b] = 0;
    for (int t = 0; t < TILES; ++t) {
        const int* p = partial + (size_t)(nh * TILES + t) * HW;
        cnt += p[4096 + c];
#pragma unroll
        for (int b = 0; b < cB; ++b) bs[b] += p[c * 32 + b];
    }
    if (mode == 0) {
        if (cnt > 0) {                       // keep old centroid if empty
            unsigned int nw = 0;
#pragma unroll
            for (int b = 0; b < cB; ++b)
                if (2 * bs[b] > cnt) nw |= (1u << b);
            cent[nh * cC + c] = nw;
        }
    } else {
        counts[nh * cC + c] = cnt;
        scn[c] = cnt;
        __syncthreads();
        if (c == 0) {
            int run = 0;
            for (int i = 0; i < cC; ++i) { int v = scn[i]; scn[i] = run; run += v; }
        }
        __syncthreads();
        moff[nh * cC + c] = scn[c];          // exclusive cluster prefix
    }
}

// ---------------- Kernel 2d: parallel stable counting-sort ranks ---------
// grid = 16 nh x 8 tiles = 128 blocks, 256 threads (1 point each)
// pos = moff[nh][c] + sum_{t'<tile} partial[t'].count[c] + in-tile stable rank
__global__ __launch_bounds__(256)
void k_rank(const int* __restrict__ cl, const int* __restrict__ partial,
            const int* __restrict__ moff, int* __restrict__ mlist)
{
    __shared__ int pre[cC];
    __shared__ int wcnt[4][cC];
    int tid = threadIdx.x, lane = tid & 63, wid = tid >> 6;
    int tile = blockIdx.x & (TILES - 1), nh = blockIdx.x / TILES;
    if (tid < cC) {
        int s = 0;
        for (int t = 0; t < tile; ++t)
            s += partial[(size_t)(nh * TILES + t) * HW + 4096 + tid];
        pre[tid] = s + moff[nh * cC + tid];
    }
    int l = tile * 256 + tid;
    int bc = cl[(size_t)nh * cL + l];
    unsigned long long ltmask = (1ull << lane) - 1ull;   // lanes below me
    int myrank = 0;
    for (int c = 0; c < cC; ++c) {
        unsigned long long m = __ballot(bc == c);
        if (lane == 0) wcnt[wid][c] = __popcll(m);
        if (bc == c) myrank = __popcll(m & ltmask);
    }
    __syncthreads();
    int off = pre[bc] + myrank;
    for (int w = 0; w < 4; ++w)
        if (w < wid) off += wcnt[w][bc];
    mlist[(size_t)nh * cL + off] = l;
}

// ---------------- Kernel 3: cluster-mean queries Qg ----------------------
// one block (64 lanes = e) per (nh,c); dense member list, batched loads,
// strict ascending-l single-accumulator chain (bit-exact vs np GEMM)
__global__ __launch_bounds__(64)
void k_qg(const float* __restrict__ q, const int* __restrict__ mlist,
          const int* __restrict__ moff, const int* __restrict__ counts,
          float* __restrict__ Qg)
{
    int b = blockIdx.x;                 // nh*cC + c
    int nh = b >> 7;
    int h = nh % cH, n = nh / cH;
    int lane = threadIdx.x;
    int off = moff[b];
    int cnt = counts[b];
    const int* ml = mlist + (size_t)nh * cL + off;
    const float* qb = q + ((size_t)n * cL * cH + h) * cE + lane;
    float acc = 0.f;
    int j = 0;
    for (; j + 4 <= cnt; j += 4) {
        int i0 = ml[j], i1 = ml[j + 1], i2 = ml[j + 2], i3 = ml[j + 3];
        float v0 = qb[(size_t)i0 * cH * cE];
        float v1 = qb[(size_t)i1 * cH * cE];
        float v2 = qb[(size_t)i2 * cH * cE];
        float v3 = qb[(size_t)i3 * cH * cE];
        acc += v0; acc += v1; acc += v2; acc += v3;    // in-order chain
    }
    for (; j < cnt; ++j) acc += qb[(size_t)ml[j] * cH * cE];
    float cs = (float)(cnt > 0 ? cnt : 1);
    Qg[(size_t)b * cE + lane] = acc / cs;
}

// ---------------- Kernel 4a: QK = Qg . k^T  (tiled GEMM, exact chains) ---
// grid = nh(16) x s-tiles(16 of 128); block 256 = 16 ty (c) x 16 tx (s)
__global__ __launch_bounds__(256)
void k_qk_gemm(const float* __restrict__ key, const float* __restrict__ Qg,
               float* __restrict__ QK)
{
    __shared__ float qgT[cE][cC + 2];      // [e][c]
    __shared__ float kT[cE][128 + 2];      // [e][s_local]
    int tid = threadIdx.x;
    int bs = blockIdx.x & 15;              // s-tile
    int nh = blockIdx.x >> 4;
    int h = nh % cH, n = nh / cH;
    const float4* qsrc = (const float4*)(Qg + (size_t)nh * cC * cE);
#pragma unroll
    for (int i = 0; i < 8; ++i) {
        int f = tid + 256 * i;
        int c = f >> 4, e4 = (f & 15) << 2;
        float4 v = qsrc[f];
        qgT[e4+0][c] = v.x; qgT[e4+1][c] = v.y; qgT[e4+2][c] = v.z; qgT[e4+3][c] = v.w;
    }
    const float* kb = key + (size_t)n * cS * cH * cE + (size_t)h * cE;
    int s0 = bs * 128;
#pragma unroll
    for (int i = 0; i < 8; ++i) {
        int f = tid + 256 * i;
        int s = f >> 4, e4 = (f & 15) << 2;
        float4 v = *(const float4*)(kb + (size_t)(s0 + s) * (cH * cE) + e4);
        kT[e4+0][s] = v.x; kT[e4+1][s] = v.y; kT[e4+2][s] = v.z; kT[e4+3][s] = v.w;
    }
    __syncthreads();
    int tx = tid & 15, ty = tid >> 4;
    float acc[8][8];
#pragma unroll
    for (int i = 0; i < 8; ++i)
#pragma unroll
        for (int j = 0; j < 8; ++j) acc[i][j] = 0.f;
    for (int e = 0; e < cE; ++e) {
        float qv[8], kv[8];
#pragma unroll
        for (int i = 0; i < 8; ++i) qv[i] = qgT[e][ty + 16 * i];
#pragma unroll
        for (int j = 0; j < 8; ++j) kv[j] = kT[e][tx + 16 * j];
#pragma unroll
        for (int i = 0; i < 8; ++i)
#pragma unroll
            for (int j = 0; j < 8; ++j)
                acc[i][j] = fmaf(qv[i], kv[j], acc[i][j]);   // ascending-e chain
    }
    float* dst = QK + (size_t)nh * cC * cS + s0;
#pragma unroll
    for (int i = 0; i < 8; ++i)
#pragma unroll
        for (int j = 0; j < 8; ++j)
            dst[(size_t)(ty + 16 * i) * cS + tx + 16 * j] = acc[i][j];
}

// ---------------- Kernel 4b: per-row top-32 + softmax -> P (in-place) ----
// one block (256 threads) per (n,h,c) row
__global__ __launch_bounds__(256)
void k_sel(float* __restrict__ QK, int* __restrict__ topk,
           float* __restrict__ abk)
{
    __shared__ float row[cS];
    __shared__ float work[cS];
    __shared__ float rv[4];
    __shared__ int   ri[4];
    __shared__ int   stopk[cK];
    __shared__ float sM, sDen;
    int tid = threadIdx.x;
    int lane = tid & 63, wid = tid >> 6;
    int b = blockIdx.x;                 // (n*H + h)*C + c
    float* qrow = QK + (size_t)b * cS;
    for (int j = 0; j < cS / 256; ++j) {
        int s = tid + j * 256;
        float v = qrow[s];
        row[s] = v; work[s] = v;
    }
    __syncthreads();
    // iterative top-32, tie -> lower index (jax.lax.top_k semantics)
    for (int itk = 0; itk < cK; ++itk) {
        float bv = -INFINITY; int bi = 0x7fffffff;
        for (int j = 0; j < cS / 256; ++j) {
            int s = tid + j * 256;
            float v = work[s];
            if (v > bv) { bv = v; bi = s; }
        }
#pragma unroll
        for (int off = 32; off; off >>= 1) {
            float ov = __shfl_xor(bv, off);
            int   oi = __shfl_xor(bi, off);
            if (ov > bv || (ov == bv && oi < bi)) { bv = ov; bi = oi; }
        }
        if (lane == 0) { rv[wid] = bv; ri[wid] = bi; }
        __syncthreads();
        if (tid == 0) {
            float v = rv[0]; int i = ri[0];
            for (int wv = 1; wv < 4; ++wv)
                if (rv[wv] > v || (rv[wv] == v && ri[wv] < i)) { v = rv[wv]; i = ri[wv]; }
            stopk[itk] = i;
            work[i] = -INFINITY;
        }
        __syncthreads();
    }
    if (tid < cK) topk[(size_t)b * cK + tid] = stopk[tid];
    // softmax over full row (TEMP=0.125 scaling exact; shift by max)
    float mv = -INFINITY;
    for (int j = 0; j < cS / 256; ++j) mv = fmaxf(mv, row[tid + j * 256]);
#pragma unroll
    for (int off = 32; off; off >>= 1) mv = fmaxf(mv, __shfl_xor(mv, off));
    if (lane == 0) rv[wid] = mv;
    __syncthreads();
    if (tid == 0) sM = fmaxf(fmaxf(rv[0], rv[1]), fmaxf(rv[2], rv[3]));
    __syncthreads();
    float M = sM;
    float psum = 0.f;
    for (int j = 0; j < cS / 256; ++j) {
        int s = tid + j * 256;
        float e = expf(0.125f * (row[s] - M));
        work[s] = e;
        psum += e;
    }
#pragma unroll
    for (int off = 32; off; off >>= 1) psum += __shfl_xor(psum, off);
    if (lane == 0) rv[wid] = psum;
    __syncthreads();
    if (tid == 0) sDen = ((rv[0] + rv[1]) + rv[2]) + rv[3];
    __syncthreads();
    float den = sDen;
    for (int j = 0; j < cS / 256; ++j) { int s = tid + j * 256; work[s] = work[s] / den; }
    __syncthreads();
    if (tid < cK) work[stopk[tid]] = 0.f;        // mask out top-k
    __syncthreads();
    // A_bottomk
    float ps = 0.f;
    for (int j = 0; j < cS / 256; ++j) ps += work[tid + j * 256];
#pragma unroll
    for (int off = 32; off; off >>= 1) ps += __shfl_xor(ps, off);
    if (lane == 0) rv[wid] = ps;
    __syncthreads();
    if (tid == 0) abk[b] = ((rv[0] + rv[1]) + rv[2]) + rv[3];
    // write P back in place (normalized, top-k zeroed)
    for (int j = 0; j < cS / 256; ++j) { int s = tid + j * 256; qrow[s] = work[s]; }
}

// ---------------- Kernel 4c: Vb_g partials = P . v (split-K GEMM) --------
// grid = nh(16) x sk(8) x ch(2);  block 256 = 16 ty (c) x 16 tx (d4)
__global__ __launch_bounds__(256)
void k_pv(const float* __restrict__ P, const float* __restrict__ val,
          float* __restrict__ part)
{
    __shared__ float pT[64][64 + 2];       // [c_local][s_sub]
    __shared__ float vT[64][cD + 4];       // [s_sub][d]
    int tid = threadIdx.x;
    int ch = blockIdx.x & 1;
    int sk = (blockIdx.x >> 1) & 7;
    int nh = blockIdx.x >> 4;
    int h = nh % cH, n = nh / cH;
    int tx = tid & 15, ty = tid >> 4;
    float acc[4][4];
#pragma unroll
    for (int i = 0; i < 4; ++i)
#pragma unroll
        for (int j = 0; j < 4; ++j) acc[i][j] = 0.f;
    const float* pb = P + ((size_t)nh * cC + ch * 64) * cS;
    const float* vb = val + (size_t)n * cS * cH * cD + (size_t)h * cD;
    for (int sub = 0; sub < CHUNK / 64; ++sub) {
        int s0 = sk * CHUNK + sub * 64;
#pragma unroll
        for (int i = 0; i < 4; ++i) {
            int f = tid + 256 * i;
            int c = f >> 4, s4 = (f & 15) << 2;
            float4 v = *(const float4*)(pb + (size_t)c * cS + s0 + s4);
            pT[c][s4+0] = v.x; pT[c][s4+1] = v.y; pT[c][s4+2] = v.z; pT[c][s4+3] = v.w;
        }
#pragma unroll
        for (int i = 0; i < 4; ++i) {
            int f = tid + 256 * i;
            int ss = f >> 4, d4 = (f & 15) << 2;
            float4 v = *(const float4*)(vb + (size_t)(s0 + ss) * (cH * cD) + d4);
            vT[ss][d4+0] = v.x; vT[ss][d4+1] = v.y; vT[ss][d4+2] = v.z; vT[ss][d4+3] = v.w;
        }
        __syncthreads();
        for (int ss = 0; ss < 64; ++ss) {
            float pv[4];
#pragma unroll
            for (int i = 0; i < 4; ++i) pv[i] = pT[ty + 16 * i][ss];
            float4 vv = *(const float4*)&vT[ss][tx * 4];
#pragma unroll
            for (int i = 0; i < 4; ++i) {
                acc[i][0] = fmaf(pv[i], vv.x, acc[i][0]);
                acc[i][1] = fmaf(pv[i], vv.y, acc[i][1]);
                acc[i][2] = fmaf(pv[i], vv.z, acc[i][2]);
                acc[i][3] = fmaf(pv[i], vv.w, acc[i][3]);
            }
        }
        __syncthreads();
    }
    float* dst = part + (((size_t)sk * cNH + nh) * cC + ch * 64) * cD;
#pragma unroll
    for (int i = 0; i < 4; ++i) {
        float4 o; o.x = acc[i][0]; o.y = acc[i][1]; o.z = acc[i][2]; o.w = acc[i][3];
        *(float4*)(dst + (size_t)(ty + 16 * i) * cD + tx * 4) = o;
    }
}

// ---------------- Kernel 4d: reduce split-K partials ---------------------
__global__ __launch_bounds__(256)
void k_red(const float* __restrict__ part, float* __restrict__ vbg)
{
    int i = blockIdx.x * 256 + threadIdx.x;      // over 16*128*64 = 131072
    float acc = 0.f;
    for (int sk = 0; sk < SK; ++sk) acc += part[(size_t)sk * (cNH * cC * cD) + i];
    vbg[i] = acc;
}

// ---------------- Kernel 5: per-query epilogue ---------------------------
// one wave (64 lanes) per query, 4 waves per block
__global__ __launch_bounds__(256)
void k_out(const float* __restrict__ q, const float* __restrict__ key,
           const float* __restrict__ val, const int* __restrict__ cl,
           const float* __restrict__ abk, const float* __restrict__ vbg,
           const int* __restrict__ topk, float* __restrict__ out)
{
    __shared__ float klds[4][cK][cE + 2];
    __shared__ float qlds[4][cE];
    __shared__ float qks[4][cK];
    __shared__ int   st[4][cK];
    int tid = threadIdx.x, lane = tid & 63, wid = tid >> 6;
    int qidx = blockIdx.x * 4 + wid;        // (n*H + h)*L + l
    int l = qidx % cL, nh = qidx / cL;
    int h = nh % cH, n = nh / cH;
    int c = cl[qidx];
    const int* tk = topk + ((size_t)nh * cC + c) * cK;
    if (lane < cK) st[wid][lane] = tk[lane];
    qlds[wid][lane] = q[(((size_t)n * cL + l) * cH + h) * cE + lane];
    __syncthreads();
    const float* kb = key + ((size_t)n * cS * cH + h) * cE;
    for (int j = 0; j < cK; ++j) {
        int t = st[wid][j];
        klds[wid][j][lane] = kb[(size_t)t * cH * cE + lane];
    }
    __syncthreads();
    if (lane < cK) {
        float acc = 0.f;
#pragma unroll
        for (int e = 0; e < cE; ++e)
            acc = fmaf(qlds[wid][e], klds[wid][lane][e], acc);
        qks[wid][lane] = acc;
    }
    __syncthreads();
    float m = -INFINITY;
#pragma unroll
    for (int j = 0; j < cK; ++j) m = fmaxf(m, qks[wid][j]);
    float den = 0.f;
    float ev[cK];
#pragma unroll
    for (int j = 0; j < cK; ++j) { float e = expf(0.125f * (qks[wid][j] - m)); ev[j] = e; den += e; }
    float scale = 1.0f - abk[(size_t)nh * cC + c];
#pragma unroll
    for (int j = 0; j < cK; ++j) ev[j] = (ev[j] / den) * scale;   // A_s
    const float* vb = val + ((size_t)n * cS * cH + h) * cD + lane;
    float acc = 0.f;
#pragma unroll
    for (int j = 0; j < cK; ++j) {
        int t = st[wid][j];
        acc = fmaf(ev[j], vb[(size_t)t * cH * cD], acc);
    }
    acc += vbg[((size_t)nh * cC + c) * cD + lane];
    out[(((size_t)n * cL + l) * cH + h) * cD + lane] = acc;       // (N,L,H,D)
    const size_t off1 = (size_t)cN * cL * cH * cD;
    const size_t off2 = off1 + (size_t)cN * cH * cL * cK;
    if (lane < cK) {
        out[off1 + (size_t)qidx * cK + lane] = (float)st[wid][lane];  // sparse_index
        out[off2 + (size_t)qidx * cK + lane] = ev[lane];              // A_topk
    }
}

// ---------------- launch -------------------------------------------------
extern "C" void kernel_launch(void* const* d_in, const int* in_sizes, int n_in,
                              void* d_out, int out_size, void* d_ws, size_t ws_size,
                              hipStream_t stream)
{
    (void)in_sizes; (void)n_in; (void)out_size; (void)ws_size;
    const float* q      = (const float*)d_in[0];
    const float* key    = (const float*)d_in[1];
    const float* val    = (const float*)d_in[2];
    const float* planes = (const float*)d_in[3];
    char* w = (char*)d_ws;
    unsigned int* bits = (unsigned int*)w;  w += (size_t)cN * cH * cL * 4;
    int*   cl     = (int*)w;                w += (size_t)cN * cH * cL * 4;
    int*   counts = (int*)w;                w += (size_t)cN * cH * cC * 4;
    float* abk    = (float*)w;              w += (size_t)cN * cH * cC * 4;
    float* Qg     = (float*)w;              w += (size_t)cN * cH * cC * cE * 4;
    float* vbg    = (float*)w;              w += (size_t)cN * cH * cC * cD * 4;
    int*   topkp  = (int*)w;                w += (size_t)cN * cH * cC * cK * 4;
    float* QK     = (float*)w;              w += (size_t)cNH * cC * cS * 4;      // 16 MB (QK -> P in place)
    float* part   = (float*)w;              w += (size_t)SK * cNH * cC * cD * 4; // 4 MB
    unsigned int* cent = (unsigned int*)w;  w += (size_t)cNH * cC * 4;           // 8 KB
    int*   partial = (int*)w;               w += (size_t)cNH * TILES * HW * 4;   // 2.2 MB
    int*   mlist  = (int*)w;                w += (size_t)cNH * cL * 4;           // 128 KB
    int*   moff   = (int*)w;                w += (size_t)cNH * cC * 4;           // 8 KB
    float* out = (float*)d_out;

    k_bits   <<<(cN * cH * cL) / 256, 256, 0, stream>>>(q, planes, bits);
    k_init   <<<(cNH * cC) / 256, 256, 0, stream>>>(bits, cent);
    for (int it = 0; it < cIT; ++it) {
        k_assign <<<cNH * TILES, 256, 0, stream>>>(bits, cent, partial, cl, 0);
        k_update <<<cNH, 128, 0, stream>>>(partial, cent, counts, moff, 0);
    }
    k_assign <<<cNH * TILES, 256, 0, stream>>>(bits, cent, partial, cl, 1);
    k_update <<<cNH, 128, 0, stream>>>(partial, cent, counts, moff, 1);
    k_rank   <<<cNH * TILES, 256, 0, stream>>>(cl, partial, moff, mlist);
    k_qg     <<<cNH * cC, 64, 0, stream>>>(q, mlist, moff, counts, Qg);
    k_qk_gemm<<<cNH * 16, 256, 0, stream>>>(key, Qg, QK);
    k_sel    <<<cNH * cC, 256, 0, stream>>>(QK, topkp, abk);
    k_pv     <<<cNH * SK * 2, 256, 0, stream>>>(QK, val, part);
    k_red    <<<(cNH * cC * cD) / 256, 256, 0, stream>>>(part, vbg);
    k_out    <<<(cN * cH * cL) / 4, 256, 0, stream>>>(q, key, val, cl, abk, vbg, topkp, out);
}